// Round 1
// 1971.086 us; speedup vs baseline: 1.0813x; 1.0813x over previous
//
#include <hip/hip_runtime.h>

// ---------- sizes ----------
#define BB_   2
#define LL_   2048
#define DD_   2048
#define HV_   32
#define HK_   16
#define MM_   (BB_*LL_)          // 4096 rows
#define KEYD_ 2048
#define VALD_ 4096
#define CONVD_ 8192

typedef _Float16 half8v  __attribute__((ext_vector_type(8)));
typedef _Float16 half4v  __attribute__((ext_vector_type(4)));
typedef float    f32x4   __attribute__((ext_vector_type(4)));
typedef float    f32x2   __attribute__((ext_vector_type(2)));
typedef unsigned int uint4v __attribute__((ext_vector_type(4)));

// async global->LDS DMA, 16B/lane: LDS dest = wave-uniform base + lane*16
typedef __attribute__((address_space(3))) unsigned int  u32_lds;
typedef __attribute__((address_space(1))) const unsigned int u32_glb;
__device__ __forceinline__ void async16(const _Float16* g, _Float16* l) {
    __builtin_amdgcn_global_load_lds((u32_glb*)g, (u32_lds*)l, 16, 0, 0);
}
__device__ __forceinline__ void async16f(const float* g, float* l) {
    __builtin_amdgcn_global_load_lds((u32_glb*)g, (u32_lds*)l, 16, 0, 0);
}

// quad-perm DPP cross-lane adds (xor1 / xor2 within each quad) — VALU-latency,
// replaces ds_swizzle-class __shfl_xor on the serial S->S chain.
__device__ __forceinline__ float dpp_xor1(float x) {
    int r = __builtin_amdgcn_update_dpp(0, __builtin_bit_cast(int, x), 0xB1, 0xF, 0xF, true);
    return __builtin_bit_cast(float, r);
}
__device__ __forceinline__ float dpp_xor2(float x) {
    int r = __builtin_amdgcn_update_dpp(0, __builtin_bit_cast(int, x), 0x4E, 0xF, 0xF, true);
    return __builtin_bit_cast(float, r);
}

// ===================== convert f32 -> f16 (vectorized) =====================
__global__ __launch_bounds__(256) void k_convert(const float* __restrict__ src,
                                                 _Float16* __restrict__ dst, int n4) {
    int i = blockIdx.x * 256 + threadIdx.x;
    if (i < n4) {
        f32x4 v = *(const f32x4*)(src + (size_t)i * 4);
        half4v h;
        h.x = (_Float16)v.x; h.y = (_Float16)v.y; h.z = (_Float16)v.z; h.w = (_Float16)v.w;
        *(half4v*)(dst + (size_t)i * 4) = h;
    }
}

// ============ convert + transpose: src f32 [K][N] -> dst f16 [N][K] ============
__global__ __launch_bounds__(256) void k_transpose(const float* __restrict__ src,
                                                   _Float16* __restrict__ dst, int K, int N) {
    __shared__ float tile[32][33];
    int tx = threadIdx.x & 31, ty = threadIdx.x >> 5;      // 32 x 8
    int n0 = blockIdx.x * 32, k0 = blockIdx.y * 32;
#pragma unroll
    for (int j = 0; j < 4; j++)
        tile[ty + j * 8][tx] = src[(size_t)(k0 + ty + j * 8) * N + n0 + tx];
    __syncthreads();
#pragma unroll
    for (int j = 0; j < 4; j++)
        dst[(size_t)(n0 + ty + j * 8) * K + k0 + tx] = (_Float16)tile[tx][ty + j * 8];
}

// ===================== GEMM: C[M][N] = A[M][K] * Bt[N][K]^T =====================
// f16 inputs, fp32 accumulate, 128x128 tile, BK=32, global_load_lds staging (m97-style).
template <bool OUT_F16>
__global__ __launch_bounds__(256) void k_gemm(const _Float16* __restrict__ A,
                                              const _Float16* __restrict__ Bt,
                                              void* __restrict__ Cv,
                                              int Mdim, int Ndim, int Kdim) {
    __shared__ __align__(16) _Float16 As[128 * 32];   // 8KB
    __shared__ __align__(16) _Float16 Bs[128 * 32];   // 8KB
    const int m0 = blockIdx.y * 128, n0 = blockIdx.x * 128;
    const int t = threadIdx.x;
    const int wave = t >> 6, lane = t & 63;
    const int wm = wave & 1, wn = wave >> 1;           // 2x2 waves of 64x64
    const int r16 = lane & 15, quad = lane >> 4;

    const int ci0 = wave * 64 + lane;          // [0,256)
    const int ci1 = 256 + ci0;                 // [256,512)
    const _Float16* gA0 = A  + (size_t)(m0 + (ci0 >> 2)) * Kdim + (ci0 & 3) * 8;
    const _Float16* gA1 = A  + (size_t)(m0 + (ci1 >> 2)) * Kdim + (ci1 & 3) * 8;
    const _Float16* gB0 = Bt + (size_t)(n0 + (ci0 >> 2)) * Kdim + (ci0 & 3) * 8;
    const _Float16* gB1 = Bt + (size_t)(n0 + (ci1 >> 2)) * Kdim + (ci1 & 3) * 8;
    _Float16* lA0 = As + wave * 512;
    _Float16* lA1 = As + 2048 + wave * 512;
    _Float16* lB0 = Bs + wave * 512;
    _Float16* lB1 = Bs + 2048 + wave * 512;

    f32x4 acc[4][4];
#pragma unroll
    for (int i = 0; i < 4; i++)
#pragma unroll
        for (int j = 0; j < 4; j++) acc[i][j] = (f32x4){0.f, 0.f, 0.f, 0.f};

    for (int k0 = 0; k0 < Kdim; k0 += 32) {
        async16(gA0 + k0, lA0);
        async16(gA1 + k0, lA1);
        async16(gB0 + k0, lB0);
        async16(gB1 + k0, lB1);
        __syncthreads();
        half8v af[4], bf[4];
#pragma unroll
        for (int i = 0; i < 4; i++) {
            af[i] = *(const half8v*)(&As[(wm * 64 + i * 16 + r16) * 32 + quad * 8]);
            bf[i] = *(const half8v*)(&Bs[(wn * 64 + i * 16 + r16) * 32 + quad * 8]);
        }
#pragma unroll
        for (int i = 0; i < 4; i++)
#pragma unroll
            for (int j = 0; j < 4; j++)
                acc[i][j] = __builtin_amdgcn_mfma_f32_16x16x32_f16(af[i], bf[j], acc[i][j], 0, 0, 0);
        __syncthreads();
    }
#pragma unroll
    for (int i = 0; i < 4; i++)
#pragma unroll
        for (int j = 0; j < 4; j++)
#pragma unroll
            for (int r = 0; r < 4; r++) {
                int rg = m0 + wm * 64 + i * 16 + quad * 4 + r;
                int cg = n0 + wn * 64 + j * 16 + r16;
                float v = acc[i][j][r];
                if (OUT_F16) ((_Float16*)Cv)[(size_t)rg * Ndim + cg] = (_Float16)v;
                else         ((float*)Cv)[(size_t)rg * Ndim + cg] = v;
            }
}

// ========== b/a projections (N=32 each) + beta/g activation, one row/block ==========
__global__ __launch_bounds__(256) void k_ba(const float* __restrict__ hidden,
                                            const float* __restrict__ Wb,
                                            const float* __restrict__ Wa,
                                            const float* __restrict__ dt_bias,
                                            const float* __restrict__ A_log,
                                            float* __restrict__ gout,
                                            float* __restrict__ betaout) {
    int row = blockIdx.x;
    __shared__ float xs[2048];
    __shared__ float part[4][64];
    int t = threadIdx.x;
    for (int c = t; c < 512; c += 256)
        *(f32x4*)&xs[c * 4] = *(const f32x4*)&hidden[(size_t)row * 2048 + c * 4];
    __syncthreads();
    int col = t & 63, kq = t >> 6;
    const float* W = (col < 32) ? Wb : Wa;
    int cc = col & 31;
    float p = 0.f;
#pragma unroll 4
    for (int k = kq * 512; k < kq * 512 + 512; k++)
        p += xs[k] * W[(size_t)k * 32 + cc];
    part[kq][col] = p;
    __syncthreads();
    if (t < 64) {
        float v = part[0][t] + part[1][t] + part[2][t] + part[3][t];
        if (t < 32) {
            betaout[(size_t)row * 32 + t] = 1.f / (1.f + __expf(-v));
        } else {
            int hh = t - 32;
            float x = v + dt_bias[hh];
            float sp = (x > 20.f) ? x : log1pf(__expf(x));
            gout[(size_t)row * 32 + hh] = -__expf(A_log[hh]) * sp;
        }
    }
}

// ===== causal depthwise conv (K=4) + SiLU + split + l2norm(q,k), one row/block =====
// q,k out: f32 (scan wants cvt-free f32 math); v out: f16
__global__ __launch_bounds__(256) void k_conv(const _Float16* __restrict__ mixed,
                                              const float* __restrict__ conv_w,
                                              float* __restrict__ qout,
                                              float* __restrict__ kout,
                                              _Float16* __restrict__ vout) {
    int row = blockIdx.x;
    int l = row & (LL_ - 1);
    __shared__ float yv[CONVD_];
    __shared__ float red[256];
    __shared__ float rinvs[32];
    int t = threadIdx.x;
    for (int c = t; c < CONVD_; c += 256) {
        float acc = 0.f;
#pragma unroll
        for (int j = 0; j < 4; j++) {
            int sl = l - 3 + j;          // per-sequence causal pad
            if (sl >= 0) acc += (float)mixed[(size_t)(row - 3 + j) * CONVD_ + c] * conv_w[c * 4 + j];
        }
        yv[c] = acc / (1.f + __expf(-acc));            // SiLU
    }
    __syncthreads();
    int seg = t >> 3, j8 = t & 7;
    int base = (seg < 16) ? seg * 128 : 2048 + (seg - 16) * 128;
    float ss = 0.f;
#pragma unroll
    for (int i = 0; i < 16; i++) { float vv = yv[base + j8 * 16 + i]; ss += vv * vv; }
    red[t] = ss;
    __syncthreads();
    if (t < 32) {
        float tot = 0.f;
#pragma unroll
        for (int jj = 0; jj < 8; jj++) tot += red[t * 8 + jj];
        rinvs[t] = rsqrtf(tot + 1e-6f);
    }
    __syncthreads();
    for (int c = t; c < CONVD_; c += 256) {
        float y = yv[c];
        if (c < 2048) {
            qout[(size_t)row * 2048 + c] = y * rinvs[c >> 7] * 0.08838834764831843f;
        } else if (c < 4096) {
            int c2 = c - 2048;
            kout[(size_t)row * 2048 + c2] = y * rinvs[16 + (c2 >> 7)];
        } else {
            vout[(size_t)row * 4096 + (c - 4096)] = (_Float16)y;
        }
    }
}

// ===================== gated delta-rule scan =====================
// R7: LDS-resident k/q prefetch pipeline.
// WHY: R6 kept the 3-step k/q prefetch in registers (6 bufs x 32 f32 = 192
// VGPR) but the compiler allocated only 124 VGPR -> it SANK the loads next to
// their uses, collapsing lookahead to ~0 and exposing full L2/L3 latency every
// step (measured 1434 cyc/step, VALUBusy 12.6%). Fix: stage k+q rows in an
// 8-slot LDS ring via global_load_lds (1 async16 stages both: lanes 0-31 -> k,
// lanes 32-63 -> q, source pre-permuted per-lane so ds_read_b128 is
// bank-conflict-free). Prefetch depth 7 costs ZERO registers and cannot be
// rescheduled away. Sync: hand-counted s_waitcnt vmcnt(N) + "memory" fences
// pinning per-phase VMEM groups {store, async, v/g/b}; counts chosen safe
// whether g/b compile to vector or scalar loads (peeled first 3 steps use the
// tighter prologue count). Lane roles switched to dvo=l>>2 / dkq=l&3 so the
// two on-chain cross-lane reduces are quad-perm DPP adds (VALU latency) not
// ds-shuffles. Reduction tree shape identical -> bit-identical numerics.
__global__ __launch_bounds__(64, 1) void k_scan(const float* __restrict__ q,
                                                const float* __restrict__ k,
                                                const _Float16* __restrict__ v,
                                                const float* __restrict__ g,
                                                const float* __restrict__ beta,
                                                _Float16* __restrict__ o) {
    int bid = blockIdx.x;          // 512 = 16 members * 32 groups
    int member = bid >> 5;         // 0..15: (h&1)*8 + dv-tile
    int G = bid & 31;              // group (b,hk): bid%8 == G%8 -> same XCD
    int b = G >> 4, hk = G & 15;
    int h = hk * 2 + (member >> 3);
    int dvt = member & 7;
    int l = threadIdx.x;
    int dvo = l >> 2, dkq = l & 3;
    int dv = dvt * 16 + dvo;

    __shared__ __align__(16) float kq[8][256];   // 8 x (128 k + 128 q) = 8KB ring

    const float*    krow = k + ((size_t)(b * LL_) * 16 + hk) * 128;
    const float*    qrow = q + ((size_t)(b * LL_) * 16 + hk) * 128;
    const _Float16* vb_ = v + ((size_t)(b * LL_) * 32 + h) * 128 + dv;
    const float*    gb_ = g + (size_t)(b * LL_) * 32 + h;
    const float*    bb_ = beta + (size_t)(b * LL_) * 32 + h;
    _Float16*       ob_ = o + ((size_t)(b * LL_) * 32 + h) * 128 + dv;

    // per-lane DMA source: lanes 0-31 stage k, 32-63 stage q. Source chunk is
    // permuted (m173 pattern): LDS position p holds global chunk (p&3)*8+(p>>2),
    // so the read of chunk (dkq*8+c) lands at float offset c*16 + dkq*4 —
    // 64B-contiguous across the 4 dkq groups => conflict-free ds_read_b128.
    {
    }
    int jl = l & 31;
    int pj = (jl & 3) * 8 + (jl >> 2);
    const float* gsrc = ((l >> 5) ? qrow : krow) + (size_t)pj * 4;

    f32x2 s2[16];
#pragma unroll
    for (int i = 0; i < 16; i++) s2[i] = (f32x2){0.f, 0.f};

    float vA, gA, bA, vB, gB, bB, vC, gC, bC;

#define SB __builtin_amdgcn_sched_barrier(0)

#define ASYNC(T)                                                          \
    do {                                                                  \
        int Tc_ = ((T) < LL_) ? (T) : (LL_ - 1);                          \
        async16f(gsrc + (size_t)Tc_ * 2048, &kq[(T) & 7][0]);             \
    } while (0)

#define LDVGB(VV, GG, BV, T)                                              \
    do {                                                                  \
        int T_ = ((T) < LL_) ? (T) : (LL_ - 1);                           \
        VV = (float)vb_[(size_t)T_ * 4096];                               \
        GG = gb_[(size_t)T_ * 32];                                        \
        BV = bb_[(size_t)T_ * 32];                                        \
    } while (0)

// WN literal: min "ops after ASYNC(T)" in the vmcnt FIFO at this point, so the
// wait retires the DMA that filled slot (T)&7 before any ds_read touches it.
#define STEPX(VV, GG, BV, T, WN)                                          \
    do {                                                                  \
        const float* kqb_ = &kq[(T) & 7][0];                              \
        asm volatile("s_waitcnt vmcnt(" WN ")" ::: "memory");             \
        f32x4 KB[8], QB[8];                                               \
        _Pragma("unroll")                                                 \
        for (int c = 0; c < 8; c++) {                                     \
            KB[c] = *(const f32x4*)(kqb_ + c * 16 + dkq * 4);             \
            QB[c] = *(const f32x4*)(kqb_ + 128 + c * 16 + dkq * 4);       \
        }                                                                 \
        float eg = __expf(GG);                                            \
        f32x2 a0 = {0.f, 0.f}, a1 = {0.f, 0.f}, a2 = {0.f, 0.f}, a3 = {0.f, 0.f}; \
        _Pragma("unroll")                                                 \
        for (int c = 0; c < 8; c += 2) {                                  \
            a0 += KB[c].xy     * s2[2 * c];                               \
            a1 += KB[c].zw     * s2[2 * c + 1];                           \
            a2 += KB[c + 1].xy * s2[2 * c + 2];                           \
            a3 += KB[c + 1].zw * s2[2 * c + 3];                           \
        }                                                                 \
        f32x2 asum = (a0 + a1) + (a2 + a3);                               \
        float kv = (asum.x + asum.y) * eg;                                \
        kv += dpp_xor1(kv);                                               \
        kv += dpp_xor2(kv);                                               \
        float dlt = ((VV) - kv) * (BV);                                   \
        f32x2 eg2 = {eg, eg}, dl2 = {dlt, dlt};                           \
        f32x2 o0 = {0.f, 0.f}, o1 = {0.f, 0.f}, o2 = {0.f, 0.f}, o3 = {0.f, 0.f}; \
        _Pragma("unroll")                                                 \
        for (int c = 0; c < 8; c += 2) {                                  \
            s2[2 * c]     = s2[2 * c]     * eg2 + KB[c].xy     * dl2;     \
            s2[2 * c + 1] = s2[2 * c + 1] * eg2 + KB[c].zw     * dl2;     \
            s2[2 * c + 2] = s2[2 * c + 2] * eg2 + KB[c + 1].xy * dl2;     \
            s2[2 * c + 3] = s2[2 * c + 3] * eg2 + KB[c + 1].zw * dl2;     \
            o0 += QB[c].xy     * s2[2 * c];                               \
            o1 += QB[c].zw     * s2[2 * c + 1];                           \
            o2 += QB[c + 1].xy * s2[2 * c + 2];                          \
            o3 += QB[c + 1].zw * s2[2 * c + 3];                           \
        }                                                                 \
        f32x2 osum = (o0 + o1) + (o2 + o3);                               \
        float ov = osum.x + osum.y;                                       \
        ov += dpp_xor1(ov);                                               \
        ov += dpp_xor2(ov);                                               \
        if ((l & 3) == 0) ob_[(size_t)(T) * 4096] = (_Float16)ov;         \
    } while (0)

    // ---- order-pinned prologue: FIFO = A0,A1,V0,A2,V1,A3,V2,A4,A5,A6 ----
    ASYNC(0); SB;
    ASYNC(1); SB;
    LDVGB(vA, gA, bA, 0); SB;
    ASYNC(2); SB;
    LDVGB(vB, gB, bB, 1); SB;
    ASYNC(3); SB;
    LDVGB(vC, gC, bC, 2); SB;
    ASYNC(4); SB;
    ASYNC(5); SB;
    ASYNC(6); SB;

    // ---- peeled ramp-up (tighter waits while store FIFO entries are missing) ----
    STEPX(vA, gA, bA, 0, "9");  ASYNC(7); LDVGB(vA, gA, bA, 3);
    STEPX(vB, gB, bB, 1, "9");  ASYNC(8); LDVGB(vB, gB, bB, 4);
    STEPX(vC, gC, bC, 2, "9");  ASYNC(9); LDVGB(vC, gC, bC, 5);

    // ---- steady state: per-phase group {store(t), ASYNC(t+7), vgb(t+3)} ----
    for (int t = 3; t < LL_; t += 3) {
        STEPX(vA, gA, bA, t, "12");
        ASYNC(t + 7); LDVGB(vA, gA, bA, t + 3);
        if (t + 1 < LL_) {
            STEPX(vB, gB, bB, t + 1, "12");
            ASYNC(t + 8); LDVGB(vB, gB, bB, t + 4);
        }
        if (t + 2 < LL_) {
            STEPX(vC, gC, bC, t + 2, "12");
            ASYNC(t + 9); LDVGB(vC, gC, bC, t + 5);
        }
    }
#undef STEPX
#undef LDVGB
#undef ASYNC
#undef SB
}

// ===================== gated RMSNorm, one row/block, f16 in/out =====================
__global__ __launch_bounds__(256) void k_rmsnorm(const _Float16* __restrict__ o,
                                                 const _Float16* __restrict__ z,
                                                 const float* __restrict__ norm_w,
                                                 _Float16* __restrict__ gn) {
    int row = blockIdx.x;
    __shared__ float gv[4096];
    __shared__ float red[256];
    __shared__ float rinv[32];
    int t = threadIdx.x;
    int h = t >> 3, j = t & 7;
    size_t base = (size_t)row * 4096 + h * 128 + j * 16;
    float ss = 0.f;
#pragma unroll
    for (int i = 0; i < 16; i++) {
        float ov = (float)o[base + i];
        float zv = (float)z[base + i];
        float gg = ov * zv / (1.f + __expf(-zv));
        gv[h * 128 + j * 16 + i] = gg;
        ss += gg * gg;
    }
    red[t] = ss;
    __syncthreads();
    if (t < 32) {
        float tot = 0.f;
#pragma unroll
        for (int jj = 0; jj < 8; jj++) tot += red[t * 8 + jj];
        rinv[t] = rsqrtf(tot * (1.f / 128.f) + 1e-6f);
    }
    __syncthreads();
#pragma unroll
    for (int i = 0; i < 16; i++) {
        int idx = h * 128 + j * 16 + i;
        gn[(size_t)row * 4096 + idx] = (_Float16)(gv[idx] * rinv[h] * norm_w[idx & 127]);
    }
}

// ===================== launch =====================
// Workspace (145 MB + d_out as scratch; aliases stream-ordered):
//   [  0, 16) XH f16 (r: GEMM1,GEMM2)      -> GN f16 [0,32) (w: rmsnorm after GEMM2)
//   [ 16, 48) WQKVT f16 (r: GEMM1)         -> VB f16 (w: conv, r: scan)
//   [ 48,112) MIXED f16 (w: GEMM1, r: conv)-> OB f16 [48,80) (w: scan)
//                                          -> WZT f16 [80,96)
//   [ 96,128) ZH f16 (w: GEMM2 after scan; overlaps dead MIXED tail + dead KB head)
//   [112,144) KB f32 (w: conv, r: scan)    -> WOUTT f16 [128,144) (after scan)
//   [144,145) GB + BBUF f32
//   d_out (32 MiB f32) = QB (w: conv, r: scan, overwritten by GEMM3 at end)
extern "C" void kernel_launch(void* const* d_in, const int* in_sizes, int n_in,
                              void* d_out, int out_size, void* d_ws, size_t ws_size,
                              hipStream_t stream) {
    const float* hidden  = (const float*)d_in[0];
    const float* W_qkv   = (const float*)d_in[1];
    const float* W_z     = (const float*)d_in[2];
    const float* W_b     = (const float*)d_in[3];
    const float* W_a     = (const float*)d_in[4];
    const float* conv_w  = (const float*)d_in[5];
    const float* dt_bias = (const float*)d_in[6];
    const float* A_log   = (const float*)d_in[7];
    const float* norm_w  = (const float*)d_in[8];
    const float* W_out   = (const float*)d_in[9];
    float* out = (float*)d_out;

    const size_t MB = 1ull << 20;
    char* ws = (char*)d_ws;
    if (ws_size < 146 * MB) {
        hipMemsetAsync(d_out, 0, (size_t)out_size * sizeof(float), stream);
        return;
    }

    _Float16* XH    = (_Float16*)(ws + 0 * MB);
    _Float16* WQKVT = (_Float16*)(ws + 16 * MB);
    _Float16* MIXED = (_Float16*)(ws + 48 * MB);
    float*    QB    = out;                           // d_out as q scratch
    float*    KB    = (float*)(ws + 112 * MB);
    _Float16* VB    = (_Float16*)(ws + 16 * MB);
    _Float16* OB    = (_Float16*)(ws + 48 * MB);
    _Float16* WZT   = (_Float16*)(ws + 80 * MB);
    _Float16* ZH    = (_Float16*)(ws + 96 * MB);
    _Float16* GN    = (_Float16*)(ws + 0 * MB);
    _Float16* WOUTT = (_Float16*)(ws + 128 * MB);
    float*    GB    = (float*)(ws + 144 * MB);
    float*    BBUF  = (float*)(ws + 144 * MB + 512 * 1024);

    k_convert<<<(MM_ * DD_ / 4 + 255) / 256, 256, 0, stream>>>(hidden, XH, MM_ * DD_ / 4);
    k_transpose<<<dim3(CONVD_ / 32, DD_ / 32), 256, 0, stream>>>(W_qkv, WQKVT, DD_, CONVD_);
    k_gemm<true><<<dim3(CONVD_ / 128, MM_ / 128), 256, 0, stream>>>(XH, WQKVT, MIXED, MM_, CONVD_, DD_);
    k_ba<<<MM_, 256, 0, stream>>>(hidden, W_b, W_a, dt_bias, A_log, GB, BBUF);
    k_conv<<<MM_, 256, 0, stream>>>(MIXED, conv_w, QB, KB, VB);
    k_scan<<<512, 64, 0, stream>>>(QB, KB, VB, GB, BBUF, OB);
    k_transpose<<<dim3(VALD_ / 32, DD_ / 32), 256, 0, stream>>>(W_z, WZT, DD_, VALD_);
    k_gemm<true><<<dim3(VALD_ / 128, MM_ / 128), 256, 0, stream>>>(XH, WZT, ZH, MM_, VALD_, DD_);
    k_rmsnorm<<<MM_, 256, 0, stream>>>(OB, ZH, norm_w, GN);
    k_transpose<<<dim3(DD_ / 32, VALD_ / 32), 256, 0, stream>>>(W_out, WOUTT, VALD_, DD_);
    k_gemm<false><<<dim3(DD_ / 128, MM_ / 128), 256, 0, stream>>>(GN, WOUTT, out, MM_, DD_, VALD_);
}

// Round 2
// 1729.011 us; speedup vs baseline: 1.2326x; 1.1400x over previous
//
#include <hip/hip_runtime.h>

// ---------- sizes ----------
#define BB_   2
#define LL_   2048
#define DD_   2048
#define HV_   32
#define HK_   16
#define MM_   (BB_*LL_)          // 4096 rows
#define KEYD_ 2048
#define VALD_ 4096
#define CONVD_ 8192

typedef _Float16 half8v  __attribute__((ext_vector_type(8)));
typedef _Float16 half4v  __attribute__((ext_vector_type(4)));
typedef float    f32x4   __attribute__((ext_vector_type(4)));
typedef float    f32x2   __attribute__((ext_vector_type(2)));
typedef unsigned int uint4v __attribute__((ext_vector_type(4)));

// async global->LDS DMA, 16B/lane: LDS dest = wave-uniform base + lane*16
typedef __attribute__((address_space(3))) unsigned int  u32_lds;
typedef __attribute__((address_space(1))) const unsigned int u32_glb;
__device__ __forceinline__ void async16(const _Float16* g, _Float16* l) {
    __builtin_amdgcn_global_load_lds((u32_glb*)g, (u32_lds*)l, 16, 0, 0);
}
__device__ __forceinline__ void async16f(const float* g, float* l) {
    __builtin_amdgcn_global_load_lds((u32_glb*)g, (u32_lds*)l, 16, 0, 0);
}

// DPP cross-lane adds. xor1/xor2 = quad_perm; ror4/ror8 = row rotates within
// the 16-lane row -> together they implement a full 16-lane sum in 4 VALU-
// latency steps (after xor1+xor2 each quad is uniform; ror4 then ror8 sums
// the 4 quads of the row regardless of rotation direction).
__device__ __forceinline__ float dpp_xor1(float x) {
    int r = __builtin_amdgcn_update_dpp(0, __builtin_bit_cast(int, x), 0xB1, 0xF, 0xF, true);
    return __builtin_bit_cast(float, r);
}
__device__ __forceinline__ float dpp_xor2(float x) {
    int r = __builtin_amdgcn_update_dpp(0, __builtin_bit_cast(int, x), 0x4E, 0xF, 0xF, true);
    return __builtin_bit_cast(float, r);
}
__device__ __forceinline__ float dpp_ror4(float x) {
    int r = __builtin_amdgcn_update_dpp(0, __builtin_bit_cast(int, x), 0x124, 0xF, 0xF, true);
    return __builtin_bit_cast(float, r);
}
__device__ __forceinline__ float dpp_ror8(float x) {
    int r = __builtin_amdgcn_update_dpp(0, __builtin_bit_cast(int, x), 0x128, 0xF, 0xF, true);
    return __builtin_bit_cast(float, r);
}

// ===================== convert f32 -> f16 (vectorized) =====================
__global__ __launch_bounds__(256) void k_convert(const float* __restrict__ src,
                                                 _Float16* __restrict__ dst, int n4) {
    int i = blockIdx.x * 256 + threadIdx.x;
    if (i < n4) {
        f32x4 v = *(const f32x4*)(src + (size_t)i * 4);
        half4v h;
        h.x = (_Float16)v.x; h.y = (_Float16)v.y; h.z = (_Float16)v.z; h.w = (_Float16)v.w;
        *(half4v*)(dst + (size_t)i * 4) = h;
    }
}

// ============ convert + transpose: src f32 [K][N] -> dst f16 [N][K] ============
__global__ __launch_bounds__(256) void k_transpose(const float* __restrict__ src,
                                                   _Float16* __restrict__ dst, int K, int N) {
    __shared__ float tile[32][33];
    int tx = threadIdx.x & 31, ty = threadIdx.x >> 5;      // 32 x 8
    int n0 = blockIdx.x * 32, k0 = blockIdx.y * 32;
#pragma unroll
    for (int j = 0; j < 4; j++)
        tile[ty + j * 8][tx] = src[(size_t)(k0 + ty + j * 8) * N + n0 + tx];
    __syncthreads();
#pragma unroll
    for (int j = 0; j < 4; j++)
        dst[(size_t)(n0 + ty + j * 8) * K + k0 + tx] = (_Float16)tile[tx][ty + j * 8];
}

// ===================== GEMM: C[M][N] = A[M][K] * Bt[N][K]^T =====================
// f16 inputs, fp32 accumulate, 128x128 tile, BK=32, global_load_lds staging (m97-style).
template <bool OUT_F16>
__global__ __launch_bounds__(256) void k_gemm(const _Float16* __restrict__ A,
                                              const _Float16* __restrict__ Bt,
                                              void* __restrict__ Cv,
                                              int Mdim, int Ndim, int Kdim) {
    __shared__ __align__(16) _Float16 As[128 * 32];   // 8KB
    __shared__ __align__(16) _Float16 Bs[128 * 32];   // 8KB
    const int m0 = blockIdx.y * 128, n0 = blockIdx.x * 128;
    const int t = threadIdx.x;
    const int wave = t >> 6, lane = t & 63;
    const int wm = wave & 1, wn = wave >> 1;           // 2x2 waves of 64x64
    const int r16 = lane & 15, quad = lane >> 4;

    const int ci0 = wave * 64 + lane;          // [0,256)
    const int ci1 = 256 + ci0;                 // [256,512)
    const _Float16* gA0 = A  + (size_t)(m0 + (ci0 >> 2)) * Kdim + (ci0 & 3) * 8;
    const _Float16* gA1 = A  + (size_t)(m0 + (ci1 >> 2)) * Kdim + (ci1 & 3) * 8;
    const _Float16* gB0 = Bt + (size_t)(n0 + (ci0 >> 2)) * Kdim + (ci0 & 3) * 8;
    const _Float16* gB1 = Bt + (size_t)(n0 + (ci1 >> 2)) * Kdim + (ci1 & 3) * 8;
    _Float16* lA0 = As + wave * 512;
    _Float16* lA1 = As + 2048 + wave * 512;
    _Float16* lB0 = Bs + wave * 512;
    _Float16* lB1 = Bs + 2048 + wave * 512;

    f32x4 acc[4][4];
#pragma unroll
    for (int i = 0; i < 4; i++)
#pragma unroll
        for (int j = 0; j < 4; j++) acc[i][j] = (f32x4){0.f, 0.f, 0.f, 0.f};

    for (int k0 = 0; k0 < Kdim; k0 += 32) {
        async16(gA0 + k0, lA0);
        async16(gA1 + k0, lA1);
        async16(gB0 + k0, lB0);
        async16(gB1 + k0, lB1);
        __syncthreads();
        half8v af[4], bf[4];
#pragma unroll
        for (int i = 0; i < 4; i++) {
            af[i] = *(const half8v*)(&As[(wm * 64 + i * 16 + r16) * 32 + quad * 8]);
            bf[i] = *(const half8v*)(&Bs[(wn * 64 + i * 16 + r16) * 32 + quad * 8]);
        }
#pragma unroll
        for (int i = 0; i < 4; i++)
#pragma unroll
            for (int j = 0; j < 4; j++)
                acc[i][j] = __builtin_amdgcn_mfma_f32_16x16x32_f16(af[i], bf[j], acc[i][j], 0, 0, 0);
        __syncthreads();
    }
#pragma unroll
    for (int i = 0; i < 4; i++)
#pragma unroll
        for (int j = 0; j < 4; j++)
#pragma unroll
            for (int r = 0; r < 4; r++) {
                int rg = m0 + wm * 64 + i * 16 + quad * 4 + r;
                int cg = n0 + wn * 64 + j * 16 + r16;
                float v = acc[i][j][r];
                if (OUT_F16) ((_Float16*)Cv)[(size_t)rg * Ndim + cg] = (_Float16)v;
                else         ((float*)Cv)[(size_t)rg * Ndim + cg] = v;
            }
}

// ========== b/a projections (N=32 each) + beta/g activation, one row/block ==========
__global__ __launch_bounds__(256) void k_ba(const float* __restrict__ hidden,
                                            const float* __restrict__ Wb,
                                            const float* __restrict__ Wa,
                                            const float* __restrict__ dt_bias,
                                            const float* __restrict__ A_log,
                                            float* __restrict__ gout,
                                            float* __restrict__ betaout) {
    int row = blockIdx.x;
    __shared__ float xs[2048];
    __shared__ float part[4][64];
    int t = threadIdx.x;
    for (int c = t; c < 512; c += 256)
        *(f32x4*)&xs[c * 4] = *(const f32x4*)&hidden[(size_t)row * 2048 + c * 4];
    __syncthreads();
    int col = t & 63, kq = t >> 6;
    const float* W = (col < 32) ? Wb : Wa;
    int cc = col & 31;
    float p = 0.f;
#pragma unroll 4
    for (int k = kq * 512; k < kq * 512 + 512; k++)
        p += xs[k] * W[(size_t)k * 32 + cc];
    part[kq][col] = p;
    __syncthreads();
    if (t < 64) {
        float v = part[0][t] + part[1][t] + part[2][t] + part[3][t];
        if (t < 32) {
            betaout[(size_t)row * 32 + t] = 1.f / (1.f + __expf(-v));
        } else {
            int hh = t - 32;
            float x = v + dt_bias[hh];
            float sp = (x > 20.f) ? x : log1pf(__expf(x));
            gout[(size_t)row * 32 + hh] = -__expf(A_log[hh]) * sp;
        }
    }
}

// ===== causal depthwise conv (K=4) + SiLU + split + l2norm(q,k), one row/block =====
// q,k out: f32 (scan wants cvt-free f32 math); v out: f16
__global__ __launch_bounds__(256) void k_conv(const _Float16* __restrict__ mixed,
                                              const float* __restrict__ conv_w,
                                              float* __restrict__ qout,
                                              float* __restrict__ kout,
                                              _Float16* __restrict__ vout) {
    int row = blockIdx.x;
    int l = row & (LL_ - 1);
    __shared__ float yv[CONVD_];
    __shared__ float red[256];
    __shared__ float rinvs[32];
    int t = threadIdx.x;
    for (int c = t; c < CONVD_; c += 256) {
        float acc = 0.f;
#pragma unroll
        for (int j = 0; j < 4; j++) {
            int sl = l - 3 + j;          // per-sequence causal pad
            if (sl >= 0) acc += (float)mixed[(size_t)(row - 3 + j) * CONVD_ + c] * conv_w[c * 4 + j];
        }
        yv[c] = acc / (1.f + __expf(-acc));            // SiLU
    }
    __syncthreads();
    int seg = t >> 3, j8 = t & 7;
    int base = (seg < 16) ? seg * 128 : 2048 + (seg - 16) * 128;
    float ss = 0.f;
#pragma unroll
    for (int i = 0; i < 16; i++) { float vv = yv[base + j8 * 16 + i]; ss += vv * vv; }
    red[t] = ss;
    __syncthreads();
    if (t < 32) {
        float tot = 0.f;
#pragma unroll
        for (int jj = 0; jj < 8; jj++) tot += red[t * 8 + jj];
        rinvs[t] = rsqrtf(tot + 1e-6f);
    }
    __syncthreads();
    for (int c = t; c < CONVD_; c += 256) {
        float y = yv[c];
        if (c < 2048) {
            qout[(size_t)row * 2048 + c] = y * rinvs[c >> 7] * 0.08838834764831843f;
        } else if (c < 4096) {
            int c2 = c - 2048;
            kout[(size_t)row * 2048 + c2] = y * rinvs[16 + (c2 >> 7)];
        } else {
            vout[(size_t)row * 4096 + (c - 4096)] = (_Float16)y;
        }
    }
}

// ===================== gated delta-rule scan =====================
// R8: 4x wave-level parallelism on top of R7's LDS-ring DMA pipeline.
// WHY: R7 measured 1091us with OccupancyPercent 5.98 (2 waves/CU = half the
// SIMDs empty), VALUBusy 14.3%. The per-wave serial chain (vmcnt wait ->
// ds_read -> reduce -> S update -> reduce) is ~500+ cyc and NOTHING overlaps
// it. Fix: split dv 4x finer -> 2048 blocks (8 waves/CU, 2/SIMD), per-wave
// work /4 (4 ds_read_b128/lane-step, 8 f32 state/lane). dkq = l&15 occupies a
// full DPP row -> 16-lane reduce is 4 DPP-add steps (xor1,xor2,ror4,ror8), no
// LDS on the chain. LDS k/q layout: even chunks at slots 0-15, odd at 16-31
// (staged by permuting the per-lane GLOBAL source; LDS dest stays linear) so
// each ds_read_b128 hits 16 distinct 16B slots (2-way = free) with 4-way
// same-address broadcast across dvo. vmcnt counts re-derived: peeled phases
// use exact 9/11/13/15/17/19, steady 19 -- safe whether g/beta compile to
// SMEM or VMEM (in-order vmcnt retirement; smaller N = stronger wait).
// sched_barrier(0x6) between phases pins VMEM/DS order (count integrity) but
// lets VALU float across for cross-phase overlap.
__global__ __launch_bounds__(64, 1) void k_scan(const float* __restrict__ q,
                                                const float* __restrict__ k,
                                                const _Float16* __restrict__ v,
                                                const float* __restrict__ g,
                                                const float* __restrict__ beta,
                                                _Float16* __restrict__ o) {
    int bid = blockIdx.x;          // 2048 = 64 members * 32 groups
    int member = bid >> 5;         // 0..63: hpar*32 + dvt
    int G = bid & 31;              // group (b,hk): bid%8 == G%8 -> same XCD
    int b = G >> 4, hk = G & 15;
    int h = hk * 2 + (member >> 5);
    int dvt = member & 31;
    int l = threadIdx.x;
    int dkq = l & 15, dvo = l >> 4;
    int dv = dvt * 4 + dvo;

    __shared__ __align__(16) float kq[8][256];   // 8 x (128 k + 128 q) = 8KB ring

    const float*    krow = k + ((size_t)(b * LL_) * 16 + hk) * 128;
    const float*    qrow = q + ((size_t)(b * LL_) * 16 + hk) * 128;
    const _Float16* vb_ = v + ((size_t)(b * LL_) * 32 + h) * 128 + dv;
    const float*    gb_ = g + (size_t)(b * LL_) * 32 + h;
    const float*    bb_ = beta + (size_t)(b * LL_) * 32 + h;
    _Float16*       ob_ = o + ((size_t)(b * LL_) * 32 + h) * 128 + dv;

    // staging: lanes 0-31 stage k (LDS slots 0-31), lanes 32-63 stage q
    // (slots 32-63). Slot j holds global 16B chunk c(j): even chunks 2j at
    // j<16, odd chunks 2(j-16)+1 at j>=16. Read side: lane dkq reads its k
    // chunks {2dkq, 2dkq+1} at slots {dkq, 16+dkq} -> 16 distinct slots per
    // instruction = 2-way bank alias (free) + 4-way dvo broadcast (free).
    int jl = l & 31;
    int cj = (jl < 16) ? (2 * jl) : (2 * (jl - 16) + 1);
    const float* gsrc = ((l >> 5) ? qrow : krow) + (size_t)cj * 4;

    f32x2 s2[4];
#pragma unroll
    for (int i = 0; i < 4; i++) s2[i] = (f32x2){0.f, 0.f};

    float vA, gA, bA, vB, gB, bB, vC, gC, bC;

#define SB __builtin_amdgcn_sched_barrier(0x6)   // VALU+SALU may cross; VMEM/DS pinned

#define ASYNC(T)                                                          \
    do {                                                                  \
        int Tc_ = ((T) < LL_) ? (T) : (LL_ - 1);                          \
        async16f(gsrc + (size_t)Tc_ * 2048, &kq[(T) & 7][0]);             \
    } while (0)

#define LDVGB(VV, GG, BV, T)                                              \
    do {                                                                  \
        int T_ = ((T) < LL_) ? (T) : (LL_ - 1);                           \
        VV = (float)vb_[(size_t)T_ * 4096];                               \
        GG = gb_[(size_t)T_ * 32];                                        \
        BV = bb_[(size_t)T_ * 32];                                        \
    } while (0)

// WN: in-order vmcnt retirement => vmcnt(N) guarantees all but the N newest
// VMEM ops retired. N <= (#ops newer than ASYNC(T)) in the WORST (fewest-ops)
// case retires the DMA filling slot T&7. Smaller N is always correct, only
// deeper-waiting.
#define STEPX(VV, GG, BV, T, WN)                                          \
    do {                                                                  \
        const float* kqb_ = &kq[(T) & 7][0];                              \
        asm volatile("s_waitcnt vmcnt(" WN ")" ::: "memory");             \
        f32x4 K0 = *(const f32x4*)(kqb_ + dkq * 4);                       \
        f32x4 K1 = *(const f32x4*)(kqb_ + 64 + dkq * 4);                  \
        f32x4 Q0 = *(const f32x4*)(kqb_ + 128 + dkq * 4);                 \
        f32x4 Q1 = *(const f32x4*)(kqb_ + 192 + dkq * 4);                 \
        float eg = __expf(GG);                                            \
        f32x2 a0 = K0.xy * s2[0] + K1.xy * s2[2];                         \
        f32x2 a1 = K0.zw * s2[1] + K1.zw * s2[3];                         \
        f32x2 asum = a0 + a1;                                             \
        float kv = (asum.x + asum.y) * eg;                                \
        kv += dpp_xor1(kv);                                               \
        kv += dpp_xor2(kv);                                               \
        kv += dpp_ror4(kv);                                               \
        kv += dpp_ror8(kv);                                               \
        float dlt = ((VV) - kv) * (BV);                                   \
        f32x2 eg2 = {eg, eg}, dl2 = {dlt, dlt};                           \
        s2[0] = s2[0] * eg2 + K0.xy * dl2;                                \
        s2[1] = s2[1] * eg2 + K0.zw * dl2;                                \
        s2[2] = s2[2] * eg2 + K1.xy * dl2;                                \
        s2[3] = s2[3] * eg2 + K1.zw * dl2;                                \
        f32x2 o0 = Q0.xy * s2[0] + Q1.xy * s2[2];                         \
        f32x2 o1 = Q0.zw * s2[1] + Q1.zw * s2[3];                         \
        f32x2 osum = o0 + o1;                                             \
        float ov = osum.x + osum.y;                                       \
        ov += dpp_xor1(ov);                                               \
        ov += dpp_xor2(ov);                                               \
        ov += dpp_ror4(ov);                                               \
        ov += dpp_ror8(ov);                                               \
        if (dkq == 0) ob_[(size_t)(T) * 4096] = (_Float16)ov;             \
    } while (0)

    // ---- order-pinned prologue: FIFO = A0..A6, V0, V1, V2 ----
    ASYNC(0); SB; ASYNC(1); SB; ASYNC(2); SB; ASYNC(3); SB;
    ASYNC(4); SB; ASYNC(5); SB; ASYNC(6); SB;
    LDVGB(vA, gA, bA, 0); SB;
    LDVGB(vB, gB, bB, 1); SB;
    LDVGB(vC, gC, bC, 2); SB;

    // ---- peeled ramp-up: exact newer-op counts (SMEM-worst-case) ----
    STEPX(vA, gA, bA, 0, "9");  SB; ASYNC(7);  SB; LDVGB(vA, gA, bA, 3); SB;
    STEPX(vB, gB, bB, 1, "11"); SB; ASYNC(8);  SB; LDVGB(vB, gB, bB, 4); SB;
    STEPX(vC, gC, bC, 2, "13"); SB; ASYNC(9);  SB; LDVGB(vC, gC, bC, 5); SB;
    STEPX(vA, gA, bA, 3, "15"); SB; ASYNC(10); SB; LDVGB(vA, gA, bA, 6); SB;
    STEPX(vB, gB, bB, 4, "17"); SB; ASYNC(11); SB; LDVGB(vB, gB, bB, 7); SB;
    STEPX(vC, gC, bC, 5, "19"); SB; ASYNC(12); SB; LDVGB(vC, gC, bC, 8); SB;

    // ---- steady state: per-phase {step(t) [ends with store], ASYNC(t+7), vgb(t+3)} ----
    for (int t = 6; t < LL_; t += 3) {
        STEPX(vA, gA, bA, t, "19");
        SB; ASYNC(t + 7); SB; LDVGB(vA, gA, bA, t + 3); SB;
        if (t + 1 < LL_) {
            STEPX(vB, gB, bB, t + 1, "19");
            SB; ASYNC(t + 8); SB; LDVGB(vB, gB, bB, t + 4); SB;
        }
        if (t + 2 < LL_) {
            STEPX(vC, gC, bC, t + 2, "19");
            SB; ASYNC(t + 9); SB; LDVGB(vC, gC, bC, t + 5); SB;
        }
    }
#undef STEPX
#undef LDVGB
#undef ASYNC
#undef SB
}

// ===================== gated RMSNorm, one row/block, f16 in/out =====================
__global__ __launch_bounds__(256) void k_rmsnorm(const _Float16* __restrict__ o,
                                                 const _Float16* __restrict__ z,
                                                 const float* __restrict__ norm_w,
                                                 _Float16* __restrict__ gn) {
    int row = blockIdx.x;
    __shared__ float gv[4096];
    __shared__ float red[256];
    __shared__ float rinv[32];
    int t = threadIdx.x;
    int h = t >> 3, j = t & 7;
    size_t base = (size_t)row * 4096 + h * 128 + j * 16;
    float ss = 0.f;
#pragma unroll
    for (int i = 0; i < 16; i++) {
        float ov = (float)o[base + i];
        float zv = (float)z[base + i];
        float gg = ov * zv / (1.f + __expf(-zv));
        gv[h * 128 + j * 16 + i] = gg;
        ss += gg * gg;
    }
    red[t] = ss;
    __syncthreads();
    if (t < 32) {
        float tot = 0.f;
#pragma unroll
        for (int jj = 0; jj < 8; jj++) tot += red[t * 8 + jj];
        rinv[t] = rsqrtf(tot * (1.f / 128.f) + 1e-6f);
    }
    __syncthreads();
#pragma unroll
    for (int i = 0; i < 16; i++) {
        int idx = h * 128 + j * 16 + i;
        gn[(size_t)row * 4096 + idx] = (_Float16)(gv[idx] * rinv[h] * norm_w[idx & 127]);
    }
}

// ===================== launch =====================
// Workspace (145 MB + d_out as scratch; aliases stream-ordered):
//   [  0, 16) XH f16 (r: GEMM1,GEMM2)      -> GN f16 [0,32) (w: rmsnorm after GEMM2)
//   [ 16, 48) WQKVT f16 (r: GEMM1)         -> VB f16 (w: conv, r: scan)
//   [ 48,112) MIXED f16 (w: GEMM1, r: conv)-> OB f16 [48,80) (w: scan)
//                                          -> WZT f16 [80,96)
//   [ 96,128) ZH f16 (w: GEMM2 after scan; overlaps dead MIXED tail + dead KB head)
//   [112,144) KB f32 (w: conv, r: scan)    -> WOUTT f16 [128,144) (after scan)
//   [144,145) GB + BBUF f32
//   d_out (32 MiB f32) = QB (w: conv, r: scan, overwritten by GEMM3 at end)
extern "C" void kernel_launch(void* const* d_in, const int* in_sizes, int n_in,
                              void* d_out, int out_size, void* d_ws, size_t ws_size,
                              hipStream_t stream) {
    const float* hidden  = (const float*)d_in[0];
    const float* W_qkv   = (const float*)d_in[1];
    const float* W_z     = (const float*)d_in[2];
    const float* W_b     = (const float*)d_in[3];
    const float* W_a     = (const float*)d_in[4];
    const float* conv_w  = (const float*)d_in[5];
    const float* dt_bias = (const float*)d_in[6];
    const float* A_log   = (const float*)d_in[7];
    const float* norm_w  = (const float*)d_in[8];
    const float* W_out   = (const float*)d_in[9];
    float* out = (float*)d_out;

    const size_t MB = 1ull << 20;
    char* ws = (char*)d_ws;
    if (ws_size < 146 * MB) {
        hipMemsetAsync(d_out, 0, (size_t)out_size * sizeof(float), stream);
        return;
    }

    _Float16* XH    = (_Float16*)(ws + 0 * MB);
    _Float16* WQKVT = (_Float16*)(ws + 16 * MB);
    _Float16* MIXED = (_Float16*)(ws + 48 * MB);
    float*    QB    = out;                           // d_out as q scratch
    float*    KB    = (float*)(ws + 112 * MB);
    _Float16* VB    = (_Float16*)(ws + 16 * MB);
    _Float16* OB    = (_Float16*)(ws + 48 * MB);
    _Float16* WZT   = (_Float16*)(ws + 80 * MB);
    _Float16* ZH    = (_Float16*)(ws + 96 * MB);
    _Float16* GN    = (_Float16*)(ws + 0 * MB);
    _Float16* WOUTT = (_Float16*)(ws + 128 * MB);
    float*    GB    = (float*)(ws + 144 * MB);
    float*    BBUF  = (float*)(ws + 144 * MB + 512 * 1024);

    k_convert<<<(MM_ * DD_ / 4 + 255) / 256, 256, 0, stream>>>(hidden, XH, MM_ * DD_ / 4);
    k_transpose<<<dim3(CONVD_ / 32, DD_ / 32), 256, 0, stream>>>(W_qkv, WQKVT, DD_, CONVD_);
    k_gemm<true><<<dim3(CONVD_ / 128, MM_ / 128), 256, 0, stream>>>(XH, WQKVT, MIXED, MM_, CONVD_, DD_);
    k_ba<<<MM_, 256, 0, stream>>>(hidden, W_b, W_a, dt_bias, A_log, GB, BBUF);
    k_conv<<<MM_, 256, 0, stream>>>(MIXED, conv_w, QB, KB, VB);
    k_scan<<<2048, 64, 0, stream>>>(QB, KB, VB, GB, BBUF, OB);
    k_transpose<<<dim3(VALD_ / 32, DD_ / 32), 256, 0, stream>>>(W_z, WZT, DD_, VALD_);
    k_gemm<true><<<dim3(VALD_ / 128, MM_ / 128), 256, 0, stream>>>(XH, WZT, ZH, MM_, VALD_, DD_);
    k_rmsnorm<<<MM_, 256, 0, stream>>>(OB, ZH, norm_w, GN);
    k_transpose<<<dim3(DD_ / 32, VALD_ / 32), 256, 0, stream>>>(W_out, WOUTT, VALD_, DD_);
    k_gemm<false><<<dim3(DD_ / 128, MM_ / 128), 256, 0, stream>>>(GN, WOUTT, out, MM_, DD_, VALD_);
}

// Round 3
// 1564.457 us; speedup vs baseline: 1.3623x; 1.1052x over previous
//
#include <hip/hip_runtime.h>

// ---------- sizes ----------
#define BB_   2
#define LL_   2048
#define DD_   2048
#define HV_   32
#define HK_   16
#define MM_   (BB_*LL_)          // 4096 rows
#define KEYD_ 2048
#define VALD_ 4096
#define CONVD_ 8192

typedef _Float16 half8v  __attribute__((ext_vector_type(8)));
typedef _Float16 half4v  __attribute__((ext_vector_type(4)));
typedef float    f32x4   __attribute__((ext_vector_type(4)));
typedef float    f32x2   __attribute__((ext_vector_type(2)));
typedef unsigned int uint4v __attribute__((ext_vector_type(4)));

// async global->LDS DMA, 16B/lane: LDS dest = wave-uniform base + lane*16
typedef __attribute__((address_space(3))) unsigned int  u32_lds;
typedef __attribute__((address_space(1))) const unsigned int u32_glb;
__device__ __forceinline__ void async16(const _Float16* g, _Float16* l) {
    __builtin_amdgcn_global_load_lds((u32_glb*)g, (u32_lds*)l, 16, 0, 0);
}
__device__ __forceinline__ void async16f(const float* g, float* l) {
    __builtin_amdgcn_global_load_lds((u32_glb*)g, (u32_lds*)l, 16, 0, 0);
}

// DPP cross-lane adds. xor1/xor2 = quad_perm; ror4/ror8 = row rotates within
// the 16-lane row -> together they implement a full 16-lane sum in 4 VALU-
// latency steps.
__device__ __forceinline__ float dpp_xor1(float x) {
    int r = __builtin_amdgcn_update_dpp(0, __builtin_bit_cast(int, x), 0xB1, 0xF, 0xF, true);
    return __builtin_bit_cast(float, r);
}
__device__ __forceinline__ float dpp_xor2(float x) {
    int r = __builtin_amdgcn_update_dpp(0, __builtin_bit_cast(int, x), 0x4E, 0xF, 0xF, true);
    return __builtin_bit_cast(float, r);
}
__device__ __forceinline__ float dpp_ror4(float x) {
    int r = __builtin_amdgcn_update_dpp(0, __builtin_bit_cast(int, x), 0x124, 0xF, 0xF, true);
    return __builtin_bit_cast(float, r);
}
__device__ __forceinline__ float dpp_ror8(float x) {
    int r = __builtin_amdgcn_update_dpp(0, __builtin_bit_cast(int, x), 0x128, 0xF, 0xF, true);
    return __builtin_bit_cast(float, r);
}

// ===================== convert f32 -> f16 (vectorized) =====================
__global__ __launch_bounds__(256) void k_convert(const float* __restrict__ src,
                                                 _Float16* __restrict__ dst, int n4) {
    int i = blockIdx.x * 256 + threadIdx.x;
    if (i < n4) {
        f32x4 v = *(const f32x4*)(src + (size_t)i * 4);
        half4v h;
        h.x = (_Float16)v.x; h.y = (_Float16)v.y; h.z = (_Float16)v.z; h.w = (_Float16)v.w;
        *(half4v*)(dst + (size_t)i * 4) = h;
    }
}

// ============ convert + transpose: src f32 [K][N] -> dst f16 [N][K] ============
__global__ __launch_bounds__(256) void k_transpose(const float* __restrict__ src,
                                                   _Float16* __restrict__ dst, int K, int N) {
    __shared__ float tile[32][33];
    int tx = threadIdx.x & 31, ty = threadIdx.x >> 5;      // 32 x 8
    int n0 = blockIdx.x * 32, k0 = blockIdx.y * 32;
#pragma unroll
    for (int j = 0; j < 4; j++)
        tile[ty + j * 8][tx] = src[(size_t)(k0 + ty + j * 8) * N + n0 + tx];
    __syncthreads();
#pragma unroll
    for (int j = 0; j < 4; j++)
        dst[(size_t)(n0 + ty + j * 8) * K + k0 + tx] = (_Float16)tile[tx][ty + j * 8];
}

// ===================== GEMM: C[M][N] = A[M][K] * Bt[N][K]^T =====================
// f16 inputs, fp32 accumulate, 128x128 tile, BK=32, global_load_lds staging (m97-style).
template <bool OUT_F16>
__global__ __launch_bounds__(256) void k_gemm(const _Float16* __restrict__ A,
                                              const _Float16* __restrict__ Bt,
                                              void* __restrict__ Cv,
                                              int Mdim, int Ndim, int Kdim) {
    __shared__ __align__(16) _Float16 As[128 * 32];   // 8KB
    __shared__ __align__(16) _Float16 Bs[128 * 32];   // 8KB
    const int m0 = blockIdx.y * 128, n0 = blockIdx.x * 128;
    const int t = threadIdx.x;
    const int wave = t >> 6, lane = t & 63;
    const int wm = wave & 1, wn = wave >> 1;           // 2x2 waves of 64x64
    const int r16 = lane & 15, quad = lane >> 4;

    const int ci0 = wave * 64 + lane;          // [0,256)
    const int ci1 = 256 + ci0;                 // [256,512)
    const _Float16* gA0 = A  + (size_t)(m0 + (ci0 >> 2)) * Kdim + (ci0 & 3) * 8;
    const _Float16* gA1 = A  + (size_t)(m0 + (ci1 >> 2)) * Kdim + (ci1 & 3) * 8;
    const _Float16* gB0 = Bt + (size_t)(n0 + (ci0 >> 2)) * Kdim + (ci0 & 3) * 8;
    const _Float16* gB1 = Bt + (size_t)(n0 + (ci1 >> 2)) * Kdim + (ci1 & 3) * 8;
    _Float16* lA0 = As + wave * 512;
    _Float16* lA1 = As + 2048 + wave * 512;
    _Float16* lB0 = Bs + wave * 512;
    _Float16* lB1 = Bs + 2048 + wave * 512;

    f32x4 acc[4][4];
#pragma unroll
    for (int i = 0; i < 4; i++)
#pragma unroll
        for (int j = 0; j < 4; j++) acc[i][j] = (f32x4){0.f, 0.f, 0.f, 0.f};

    for (int k0 = 0; k0 < Kdim; k0 += 32) {
        async16(gA0 + k0, lA0);
        async16(gA1 + k0, lA1);
        async16(gB0 + k0, lB0);
        async16(gB1 + k0, lB1);
        __syncthreads();
        half8v af[4], bf[4];
#pragma unroll
        for (int i = 0; i < 4; i++) {
            af[i] = *(const half8v*)(&As[(wm * 64 + i * 16 + r16) * 32 + quad * 8]);
            bf[i] = *(const half8v*)(&Bs[(wn * 64 + i * 16 + r16) * 32 + quad * 8]);
        }
#pragma unroll
        for (int i = 0; i < 4; i++)
#pragma unroll
            for (int j = 0; j < 4; j++)
                acc[i][j] = __builtin_amdgcn_mfma_f32_16x16x32_f16(af[i], bf[j], acc[i][j], 0, 0, 0);
        __syncthreads();
    }
#pragma unroll
    for (int i = 0; i < 4; i++)
#pragma unroll
        for (int j = 0; j < 4; j++)
#pragma unroll
            for (int r = 0; r < 4; r++) {
                int rg = m0 + wm * 64 + i * 16 + quad * 4 + r;
                int cg = n0 + wn * 64 + j * 16 + r16;
                float v = acc[i][j][r];
                if (OUT_F16) ((_Float16*)Cv)[(size_t)rg * Ndim + cg] = (_Float16)v;
                else         ((float*)Cv)[(size_t)rg * Ndim + cg] = v;
            }
}

// ========== b/a projections (N=32 each) + beta/g activation, one row/block ==========
__global__ __launch_bounds__(256) void k_ba(const float* __restrict__ hidden,
                                            const float* __restrict__ Wb,
                                            const float* __restrict__ Wa,
                                            const float* __restrict__ dt_bias,
                                            const float* __restrict__ A_log,
                                            float* __restrict__ gout,
                                            float* __restrict__ betaout) {
    int row = blockIdx.x;
    __shared__ float xs[2048];
    __shared__ float part[4][64];
    int t = threadIdx.x;
    for (int c = t; c < 512; c += 256)
        *(f32x4*)&xs[c * 4] = *(const f32x4*)&hidden[(size_t)row * 2048 + c * 4];
    __syncthreads();
    int col = t & 63, kq = t >> 6;
    const float* W = (col < 32) ? Wb : Wa;
    int cc = col & 31;
    float p = 0.f;
#pragma unroll 4
    for (int k = kq * 512; k < kq * 512 + 512; k++)
        p += xs[k] * W[(size_t)k * 32 + cc];
    part[kq][col] = p;
    __syncthreads();
    if (t < 64) {
        float v = part[0][t] + part[1][t] + part[2][t] + part[3][t];
        if (t < 32) {
            betaout[(size_t)row * 32 + t] = 1.f / (1.f + __expf(-v));
        } else {
            int hh = t - 32;
            float x = v + dt_bias[hh];
            float sp = (x > 20.f) ? x : log1pf(__expf(x));
            gout[(size_t)row * 32 + hh] = -__expf(A_log[hh]) * sp;
        }
    }
}

// ===== causal depthwise conv (K=4) + SiLU + split + l2norm(q,k), one row/block =====
// q,k out: f32 (scan wants cvt-free f32 math); v out: f16
__global__ __launch_bounds__(256) void k_conv(const _Float16* __restrict__ mixed,
                                              const float* __restrict__ conv_w,
                                              float* __restrict__ qout,
                                              float* __restrict__ kout,
                                              _Float16* __restrict__ vout) {
    int row = blockIdx.x;
    int l = row & (LL_ - 1);
    __shared__ float yv[CONVD_];
    __shared__ float red[256];
    __shared__ float rinvs[32];
    int t = threadIdx.x;
    for (int c = t; c < CONVD_; c += 256) {
        float acc = 0.f;
#pragma unroll
        for (int j = 0; j < 4; j++) {
            int sl = l - 3 + j;          // per-sequence causal pad
            if (sl >= 0) acc += (float)mixed[(size_t)(row - 3 + j) * CONVD_ + c] * conv_w[c * 4 + j];
        }
        yv[c] = acc / (1.f + __expf(-acc));            // SiLU
    }
    __syncthreads();
    int seg = t >> 3, j8 = t & 7;
    int base = (seg < 16) ? seg * 128 : 2048 + (seg - 16) * 128;
    float ss = 0.f;
#pragma unroll
    for (int i = 0; i < 16; i++) { float vv = yv[base + j8 * 16 + i]; ss += vv * vv; }
    red[t] = ss;
    __syncthreads();
    if (t < 32) {
        float tot = 0.f;
#pragma unroll
        for (int jj = 0; jj < 8; jj++) tot += red[t * 8 + jj];
        rinvs[t] = rsqrtf(tot + 1e-6f);
    }
    __syncthreads();
    for (int c = t; c < CONVD_; c += 256) {
        float y = yv[c];
        if (c < 2048) {
            qout[(size_t)row * 2048 + c] = y * rinvs[c >> 7] * 0.08838834764831843f;
        } else if (c < 4096) {
            int c2 = c - 2048;
            kout[(size_t)row * 2048 + c2] = y * rinvs[16 + (c2 >> 7)];
        } else {
            vout[(size_t)row * 4096 + (c - 4096)] = (_Float16)y;
        }
    }
}

// ===================== gated delta-rule scan =====================
// R9: one-phase-ahead LDS->register prefetch on top of R8.
// WHY: R8 measured 883us, occupancy 23.6% (8 waves/CU as designed), VALUBusy
// 34%, bank conflicts 0, HBM 1.3% -- no shared resource is saturated, yet
// step time is ~1035 cyc vs a ~110 cyc arithmetic chain. The remaining serial
// cost is structural: the per-phase "memory"-pinned waitcnt + sched_barrier
// confined the 4 ds_read_b128 to their own phase, so every step pays the
// ~120 cyc LDS latency ON the chain (wait -> ds_read -> use). Fix: each phase
// ds_reads K/Q for step T+1 into a named 3-buffer register rotation (A/B/C
// matching the 3-phase unroll) right after its vmcnt wait, then computes step
// T purely from registers loaded LAST phase -- LDS latency overlaps the
// previous step's VALU chain. Waits strengthened one phase (guarantee
// ASYNC(T+1) at phase T): steady vmcnt(16), peel 9 / 8,10,12,14,16,16
// (worst-case-fewest counting, correct for SMEM or VMEM g/beta). Ring hazard
// checked: slot (T+1)&7 read in phase T is next overwritten by ASYNC(T+9),
// issued two phases later. Grid stays 2048 (at ~200cyc/step the per-CU DMA
// rate is ~41 B/cyc; doubling waves would exceed the ~56 B/cyc per-CU L2
// feed). Math/lane layout bit-identical to R8.
__global__ __launch_bounds__(64, 1) void k_scan(const float* __restrict__ q,
                                                const float* __restrict__ k,
                                                const _Float16* __restrict__ v,
                                                const float* __restrict__ g,
                                                const float* __restrict__ beta,
                                                _Float16* __restrict__ o) {
    int bid = blockIdx.x;          // 2048 = 64 members * 32 groups
    int member = bid >> 5;         // 0..63: hpar*32 + dvt
    int G = bid & 31;              // group (b,hk): bid%8 == G%8 -> same XCD
    int b = G >> 4, hk = G & 15;
    int h = hk * 2 + (member >> 5);
    int dvt = member & 31;
    int l = threadIdx.x;
    int dkq = l & 15, dvo = l >> 4;
    int dv = dvt * 4 + dvo;

    __shared__ __align__(16) float kq[8][256];   // 8 x (128 k + 128 q) = 8KB ring

    const float*    krow = k + ((size_t)(b * LL_) * 16 + hk) * 128;
    const float*    qrow = q + ((size_t)(b * LL_) * 16 + hk) * 128;
    const _Float16* vb_ = v + ((size_t)(b * LL_) * 32 + h) * 128 + dv;
    const float*    gb_ = g + (size_t)(b * LL_) * 32 + h;
    const float*    bb_ = beta + (size_t)(b * LL_) * 32 + h;
    _Float16*       ob_ = o + ((size_t)(b * LL_) * 32 + h) * 128 + dv;

    // staging: lanes 0-31 stage k (LDS slots 0-31), lanes 32-63 stage q
    // (slots 32-63). Slot j holds global 16B chunk c(j): even chunks 2j at
    // j<16, odd chunks 2(j-16)+1 at j>=16. Read side: lane dkq reads its k
    // chunks {2dkq, 2dkq+1} at slots {dkq, 16+dkq} -> 16 distinct slots per
    // instruction = 2-way bank alias (free) + 4-way dvo broadcast (free).
    int jl = l & 31;
    int cj = (jl < 16) ? (2 * jl) : (2 * (jl - 16) + 1);
    const float* gsrc = ((l >> 5) ? qrow : krow) + (size_t)cj * 4;

    f32x2 s2[4];
#pragma unroll
    for (int i = 0; i < 4; i++) s2[i] = (f32x2){0.f, 0.f};

    float vA, gA, bA, vB, gB, bB, vC, gC, bC;
    f32x4 KA0, KA1, QA0, QA1;
    f32x4 KB0, KB1, QB0, QB1;
    f32x4 KC0, KC1, QC0, QC1;

#define SB __builtin_amdgcn_sched_barrier(0x6)   // VALU+SALU may cross; VMEM/DS pinned

#define ASYNC(T)                                                          \
    do {                                                                  \
        int Tc_ = ((T) < LL_) ? (T) : (LL_ - 1);                          \
        async16f(gsrc + (size_t)Tc_ * 2048, &kq[(T) & 7][0]);             \
    } while (0)

#define LDVGB(VV, GG, BV, T)                                              \
    do {                                                                  \
        int T_ = ((T) < LL_) ? (T) : (LL_ - 1);                           \
        VV = (float)vb_[(size_t)T_ * 4096];                               \
        GG = gb_[(size_t)T_ * 32];                                        \
        BV = bb_[(size_t)T_ * 32];                                        \
    } while (0)

// PHASE(T): wait (guarantees slot T+1 landed); prefetch K/Q(T+1) -> N*;
// compute step T from C* (loaded last phase); store; ASYNC(T+7); vgb(T+3).
// WN: in-order vmcnt retirement => vmcnt(N) forces all but the N newest VMEM
// ops retired. N <= (#ops newer than ASYNC(T+1)) in the fewest-op case
// (g/beta SMEM) retires the DMA filling slot (T+1)&7. Smaller N is always
// correct, only deeper-waiting.
#define PHASE(C0, C1, C2, C3, N0, N1, N2, N3, VV, GG, BV, T, WN)          \
    do {                                                                  \
        asm volatile("s_waitcnt vmcnt(" WN ")" ::: "memory");             \
        const float* nb_ = &kq[((T) + 1) & 7][0];                         \
        N0 = *(const f32x4*)(nb_ + dkq * 4);                              \
        N1 = *(const f32x4*)(nb_ + 64 + dkq * 4);                         \
        N2 = *(const f32x4*)(nb_ + 128 + dkq * 4);                        \
        N3 = *(const f32x4*)(nb_ + 192 + dkq * 4);                        \
        float eg = __expf(GG);                                            \
        f32x2 a0 = C0.xy * s2[0] + C1.xy * s2[2];                         \
        f32x2 a1 = C0.zw * s2[1] + C1.zw * s2[3];                         \
        f32x2 asum = a0 + a1;                                             \
        float kv = (asum.x + asum.y) * eg;                                \
        kv += dpp_xor1(kv);                                               \
        kv += dpp_xor2(kv);                                               \
        kv += dpp_ror4(kv);                                               \
        kv += dpp_ror8(kv);                                               \
        float dlt = ((VV) - kv) * (BV);                                   \
        f32x2 eg2 = {eg, eg}, dl2 = {dlt, dlt};                           \
        s2[0] = s2[0] * eg2 + C0.xy * dl2;                                \
        s2[1] = s2[1] * eg2 + C0.zw * dl2;                                \
        s2[2] = s2[2] * eg2 + C1.xy * dl2;                                \
        s2[3] = s2[3] * eg2 + C1.zw * dl2;                                \
        f32x2 o0 = C2.xy * s2[0] + C3.xy * s2[2];                         \
        f32x2 o1 = C2.zw * s2[1] + C3.zw * s2[3];                         \
        f32x2 osum = o0 + o1;                                             \
        float ov = osum.x + osum.y;                                       \
        ov += dpp_xor1(ov);                                               \
        ov += dpp_xor2(ov);                                               \
        ov += dpp_ror4(ov);                                               \
        ov += dpp_ror8(ov);                                               \
        if (dkq == 0) ob_[(size_t)(T) * 4096] = (_Float16)ov;             \
        SB; ASYNC((T) + 7); SB; LDVGB(VV, GG, BV, (T) + 3); SB;           \
    } while (0)

    // ---- order-pinned prologue: FIFO = A0..A6, V0, V1, V2 ----
    ASYNC(0); SB; ASYNC(1); SB; ASYNC(2); SB; ASYNC(3); SB;
    ASYNC(4); SB; ASYNC(5); SB; ASYNC(6); SB;
    LDVGB(vA, gA, bA, 0); SB;
    LDVGB(vB, gB, bB, 1); SB;
    LDVGB(vC, gC, bC, 2); SB;

    // prologue reg-load of step 0 (slot 0): wait forces A0 (SMEM case: 10
    // ops, allow 9 -> oldest 1 = A0; VMEM case stronger, still correct)
    asm volatile("s_waitcnt vmcnt(9)" ::: "memory");
    {
        const float* nb_ = &kq[0][0];
        KA0 = *(const f32x4*)(nb_ + dkq * 4);
        KA1 = *(const f32x4*)(nb_ + 64 + dkq * 4);
        QA0 = *(const f32x4*)(nb_ + 128 + dkq * 4);
        QA1 = *(const f32x4*)(nb_ + 192 + dkq * 4);
    }

    // ---- peeled ramp-up: exact newer-than-ASYNC(T+1) counts (SMEM case) ----
    PHASE(KA0, KA1, QA0, QA1, KB0, KB1, QB0, QB1, vA, gA, bA, 0, "8");
    PHASE(KB0, KB1, QB0, QB1, KC0, KC1, QC0, QC1, vB, gB, bB, 1, "10");
    PHASE(KC0, KC1, QC0, QC1, KA0, KA1, QA0, QA1, vC, gC, bC, 2, "12");
    PHASE(KA0, KA1, QA0, QA1, KB0, KB1, QB0, QB1, vA, gA, bA, 3, "14");
    PHASE(KB0, KB1, QB0, QB1, KC0, KC1, QC0, QC1, vB, gB, bB, 4, "16");
    PHASE(KC0, KC1, QC0, QC1, KA0, KA1, QA0, QA1, vC, gC, bC, 5, "16");

    // ---- steady state ----
    for (int t = 6; t < LL_; t += 3) {
        PHASE(KA0, KA1, QA0, QA1, KB0, KB1, QB0, QB1, vA, gA, bA, t, "16");
        if (t + 1 < LL_)
            PHASE(KB0, KB1, QB0, QB1, KC0, KC1, QC0, QC1, vB, gB, bB, t + 1, "16");
        if (t + 2 < LL_)
            PHASE(KC0, KC1, QC0, QC1, KA0, KA1, QA0, QA1, vC, gC, bC, t + 2, "16");
    }
#undef PHASE
#undef LDVGB
#undef ASYNC
#undef SB
}

// ===================== gated RMSNorm, one row/block, f16 in/out =====================
__global__ __launch_bounds__(256) void k_rmsnorm(const _Float16* __restrict__ o,
                                                 const _Float16* __restrict__ z,
                                                 const float* __restrict__ norm_w,
                                                 _Float16* __restrict__ gn) {
    int row = blockIdx.x;
    __shared__ float gv[4096];
    __shared__ float red[256];
    __shared__ float rinv[32];
    int t = threadIdx.x;
    int h = t >> 3, j = t & 7;
    size_t base = (size_t)row * 4096 + h * 128 + j * 16;
    float ss = 0.f;
#pragma unroll
    for (int i = 0; i < 16; i++) {
        float ov = (float)o[base + i];
        float zv = (float)z[base + i];
        float gg = ov * zv / (1.f + __expf(-zv));
        gv[h * 128 + j * 16 + i] = gg;
        ss += gg * gg;
    }
    red[t] = ss;
    __syncthreads();
    if (t < 32) {
        float tot = 0.f;
#pragma unroll
        for (int jj = 0; jj < 8; jj++) tot += red[t * 8 + jj];
        rinv[t] = rsqrtf(tot * (1.f / 128.f) + 1e-6f);
    }
    __syncthreads();
#pragma unroll
    for (int i = 0; i < 16; i++) {
        int idx = h * 128 + j * 16 + i;
        gn[(size_t)row * 4096 + idx] = (_Float16)(gv[idx] * rinv[h] * norm_w[idx & 127]);
    }
}

// ===================== launch =====================
// Workspace (145 MB + d_out as scratch; aliases stream-ordered):
//   [  0, 16) XH f16 (r: GEMM1,GEMM2)      -> GN f16 [0,32) (w: rmsnorm after GEMM2)
//   [ 16, 48) WQKVT f16 (r: GEMM1)         -> VB f16 (w: conv, r: scan)
//   [ 48,112) MIXED f16 (w: GEMM1, r: conv)-> OB f16 [48,80) (w: scan)
//                                          -> WZT f16 [80,96)
//   [ 96,128) ZH f16 (w: GEMM2 after scan; overlaps dead MIXED tail + dead KB head)
//   [112,144) KB f32 (w: conv, r: scan)    -> WOUTT f16 [128,144) (after scan)
//   [144,145) GB + BBUF f32
//   d_out (32 MiB f32) = QB (w: conv, r: scan, overwritten by GEMM3 at end)
extern "C" void kernel_launch(void* const* d_in, const int* in_sizes, int n_in,
                              void* d_out, int out_size, void* d_ws, size_t ws_size,
                              hipStream_t stream) {
    const float* hidden  = (const float*)d_in[0];
    const float* W_qkv   = (const float*)d_in[1];
    const float* W_z     = (const float*)d_in[2];
    const float* W_b     = (const float*)d_in[3];
    const float* W_a     = (const float*)d_in[4];
    const float* conv_w  = (const float*)d_in[5];
    const float* dt_bias = (const float*)d_in[6];
    const float* A_log   = (const float*)d_in[7];
    const float* norm_w  = (const float*)d_in[8];
    const float* W_out   = (const float*)d_in[9];
    float* out = (float*)d_out;

    const size_t MB = 1ull << 20;
    char* ws = (char*)d_ws;
    if (ws_size < 146 * MB) {
        hipMemsetAsync(d_out, 0, (size_t)out_size * sizeof(float), stream);
        return;
    }

    _Float16* XH    = (_Float16*)(ws + 0 * MB);
    _Float16* WQKVT = (_Float16*)(ws + 16 * MB);
    _Float16* MIXED = (_Float16*)(ws + 48 * MB);
    float*    QB    = out;                           // d_out as q scratch
    float*    KB    = (float*)(ws + 112 * MB);
    _Float16* VB    = (_Float16*)(ws + 16 * MB);
    _Float16* OB    = (_Float16*)(ws + 48 * MB);
    _Float16* WZT   = (_Float16*)(ws + 80 * MB);
    _Float16* ZH    = (_Float16*)(ws + 96 * MB);
    _Float16* GN    = (_Float16*)(ws + 0 * MB);
    _Float16* WOUTT = (_Float16*)(ws + 128 * MB);
    float*    GB    = (float*)(ws + 144 * MB);
    float*    BBUF  = (float*)(ws + 144 * MB + 512 * 1024);

    k_convert<<<(MM_ * DD_ / 4 + 255) / 256, 256, 0, stream>>>(hidden, XH, MM_ * DD_ / 4);
    k_transpose<<<dim3(CONVD_ / 32, DD_ / 32), 256, 0, stream>>>(W_qkv, WQKVT, DD_, CONVD_);
    k_gemm<true><<<dim3(CONVD_ / 128, MM_ / 128), 256, 0, stream>>>(XH, WQKVT, MIXED, MM_, CONVD_, DD_);
    k_ba<<<MM_, 256, 0, stream>>>(hidden, W_b, W_a, dt_bias, A_log, GB, BBUF);
    k_conv<<<MM_, 256, 0, stream>>>(MIXED, conv_w, QB, KB, VB);
    k_scan<<<2048, 64, 0, stream>>>(QB, KB, VB, GB, BBUF, OB);
    k_transpose<<<dim3(VALD_ / 32, DD_ / 32), 256, 0, stream>>>(W_z, WZT, DD_, VALD_);
    k_gemm<true><<<dim3(VALD_ / 128, MM_ / 128), 256, 0, stream>>>(XH, WZT, ZH, MM_, VALD_, DD_);
    k_rmsnorm<<<MM_, 256, 0, stream>>>(OB, ZH, norm_w, GN);
    k_transpose<<<dim3(DD_ / 32, VALD_ / 32), 256, 0, stream>>>(W_out, WOUTT, VALD_, DD_);
    k_gemm<false><<<dim3(DD_ / 128, MM_ / 128), 256, 0, stream>>>(GN, WOUTT, out, MM_, DD_, VALD_);
}

// Round 8
// 1500.493 us; speedup vs baseline: 1.4204x; 1.0426x over previous
//
#include <hip/hip_runtime.h>

// ---------- sizes ----------
#define BB_   2
#define LL_   2048
#define DD_   2048
#define HV_   32
#define HK_   16
#define MM_   (BB_*LL_)          // 4096 rows
#define KEYD_ 2048
#define VALD_ 4096
#define CONVD_ 8192

typedef _Float16 half8v  __attribute__((ext_vector_type(8)));
typedef _Float16 half4v  __attribute__((ext_vector_type(4)));
typedef float    f32x4   __attribute__((ext_vector_type(4)));
typedef float    f32x2   __attribute__((ext_vector_type(2)));
typedef unsigned int uint4v __attribute__((ext_vector_type(4)));

// async global->LDS DMA, 16B/lane: LDS dest = wave-uniform base + lane*16
typedef __attribute__((address_space(3))) unsigned int  u32_lds;
typedef __attribute__((address_space(1))) const unsigned int u32_glb;
__device__ __forceinline__ void async16(const _Float16* g, _Float16* l) {
    __builtin_amdgcn_global_load_lds((u32_glb*)g, (u32_lds*)l, 16, 0, 0);
}
__device__ __forceinline__ void async16f(const float* g, float* l) {
    __builtin_amdgcn_global_load_lds((u32_glb*)g, (u32_lds*)l, 16, 0, 0);
}

// DPP cross-lane adds. xor1/xor2 = quad_perm; ror4/ror8 = row rotates within
// the 16-lane row -> together they implement a full 16-lane sum in 4 VALU-
// latency steps.
__device__ __forceinline__ float dpp_xor1(float x) {
    int r = __builtin_amdgcn_update_dpp(0, __builtin_bit_cast(int, x), 0xB1, 0xF, 0xF, true);
    return __builtin_bit_cast(float, r);
}
__device__ __forceinline__ float dpp_xor2(float x) {
    int r = __builtin_amdgcn_update_dpp(0, __builtin_bit_cast(int, x), 0x4E, 0xF, 0xF, true);
    return __builtin_bit_cast(float, r);
}
__device__ __forceinline__ float dpp_ror4(float x) {
    int r = __builtin_amdgcn_update_dpp(0, __builtin_bit_cast(int, x), 0x124, 0xF, 0xF, true);
    return __builtin_bit_cast(float, r);
}
__device__ __forceinline__ float dpp_ror8(float x) {
    int r = __builtin_amdgcn_update_dpp(0, __builtin_bit_cast(int, x), 0x128, 0xF, 0xF, true);
    return __builtin_bit_cast(float, r);
}

// ===================== convert f32 -> f16 (vectorized) =====================
__global__ __launch_bounds__(256) void k_convert(const float* __restrict__ src,
                                                 _Float16* __restrict__ dst, int n4) {
    int i = blockIdx.x * 256 + threadIdx.x;
    if (i < n4) {
        f32x4 v = *(const f32x4*)(src + (size_t)i * 4);
        half4v h;
        h.x = (_Float16)v.x; h.y = (_Float16)v.y; h.z = (_Float16)v.z; h.w = (_Float16)v.w;
        *(half4v*)(dst + (size_t)i * 4) = h;
    }
}

// ============ convert + transpose: src f32 [K][N] -> dst f16 [N][K] ============
__global__ __launch_bounds__(256) void k_transpose(const float* __restrict__ src,
                                                   _Float16* __restrict__ dst, int K, int N) {
    __shared__ float tile[32][33];
    int tx = threadIdx.x & 31, ty = threadIdx.x >> 5;      // 32 x 8
    int n0 = blockIdx.x * 32, k0 = blockIdx.y * 32;
#pragma unroll
    for (int j = 0; j < 4; j++)
        tile[ty + j * 8][tx] = src[(size_t)(k0 + ty + j * 8) * N + n0 + tx];
    __syncthreads();
#pragma unroll
    for (int j = 0; j < 4; j++)
        dst[(size_t)(n0 + ty + j * 8) * K + k0 + tx] = (_Float16)tile[tx][ty + j * 8];
}

// ===================== GEMM: C[M][N] = A[M][K] * Bt[N][K]^T =====================
// f16 inputs, fp32 accumulate, 128x128 tile, BK=32, global_load_lds staging (m97-style).
template <bool OUT_F16>
__global__ __launch_bounds__(256) void k_gemm(const _Float16* __restrict__ A,
                                              const _Float16* __restrict__ Bt,
                                              void* __restrict__ Cv,
                                              int Mdim, int Ndim, int Kdim) {
    __shared__ __align__(16) _Float16 As[128 * 32];   // 8KB
    __shared__ __align__(16) _Float16 Bs[128 * 32];   // 8KB
    const int m0 = blockIdx.y * 128, n0 = blockIdx.x * 128;
    const int t = threadIdx.x;
    const int wave = t >> 6, lane = t & 63;
    const int wm = wave & 1, wn = wave >> 1;           // 2x2 waves of 64x64
    const int r16 = lane & 15, quad = lane >> 4;

    const int ci0 = wave * 64 + lane;          // [0,256)
    const int ci1 = 256 + ci0;                 // [256,512)
    const _Float16* gA0 = A  + (size_t)(m0 + (ci0 >> 2)) * Kdim + (ci0 & 3) * 8;
    const _Float16* gA1 = A  + (size_t)(m0 + (ci1 >> 2)) * Kdim + (ci1 & 3) * 8;
    const _Float16* gB0 = Bt + (size_t)(n0 + (ci0 >> 2)) * Kdim + (ci0 & 3) * 8;
    const _Float16* gB1 = Bt + (size_t)(n0 + (ci1 >> 2)) * Kdim + (ci1 & 3) * 8;
    _Float16* lA0 = As + wave * 512;
    _Float16* lA1 = As + 2048 + wave * 512;
    _Float16* lB0 = Bs + wave * 512;
    _Float16* lB1 = Bs + 2048 + wave * 512;

    f32x4 acc[4][4];
#pragma unroll
    for (int i = 0; i < 4; i++)
#pragma unroll
        for (int j = 0; j < 4; j++) acc[i][j] = (f32x4){0.f, 0.f, 0.f, 0.f};

    for (int k0 = 0; k0 < Kdim; k0 += 32) {
        async16(gA0 + k0, lA0);
        async16(gA1 + k0, lA1);
        async16(gB0 + k0, lB0);
        async16(gB1 + k0, lB1);
        __syncthreads();
        half8v af[4], bf[4];
#pragma unroll
        for (int i = 0; i < 4; i++) {
            af[i] = *(const half8v*)(&As[(wm * 64 + i * 16 + r16) * 32 + quad * 8]);
            bf[i] = *(const half8v*)(&Bs[(wn * 64 + i * 16 + r16) * 32 + quad * 8]);
        }
#pragma unroll
        for (int i = 0; i < 4; i++)
#pragma unroll
            for (int j = 0; j < 4; j++)
                acc[i][j] = __builtin_amdgcn_mfma_f32_16x16x32_f16(af[i], bf[j], acc[i][j], 0, 0, 0);
        __syncthreads();
    }
#pragma unroll
    for (int i = 0; i < 4; i++)
#pragma unroll
        for (int j = 0; j < 4; j++)
#pragma unroll
            for (int r = 0; r < 4; r++) {
                int rg = m0 + wm * 64 + i * 16 + quad * 4 + r;
                int cg = n0 + wn * 64 + j * 16 + r16;
                float v = acc[i][j][r];
                if (OUT_F16) ((_Float16*)Cv)[(size_t)rg * Ndim + cg] = (_Float16)v;
                else         ((float*)Cv)[(size_t)rg * Ndim + cg] = v;
            }
}

// ========== b/a projections (N=32 each) + beta/g activation, one row/block ==========
__global__ __launch_bounds__(256) void k_ba(const float* __restrict__ hidden,
                                            const float* __restrict__ Wb,
                                            const float* __restrict__ Wa,
                                            const float* __restrict__ dt_bias,
                                            const float* __restrict__ A_log,
                                            float* __restrict__ gout,
                                            float* __restrict__ betaout) {
    int row = blockIdx.x;
    __shared__ float xs[2048];
    __shared__ float part[4][64];
    int t = threadIdx.x;
    for (int c = t; c < 512; c += 256)
        *(f32x4*)&xs[c * 4] = *(const f32x4*)&hidden[(size_t)row * 2048 + c * 4];
    __syncthreads();
    int col = t & 63, kq = t >> 6;
    const float* W = (col < 32) ? Wb : Wa;
    int cc = col & 31;
    float p = 0.f;
#pragma unroll 4
    for (int k = kq * 512; k < kq * 512 + 512; k++)
        p += xs[k] * W[(size_t)k * 32 + cc];
    part[kq][col] = p;
    __syncthreads();
    if (t < 64) {
        float v = part[0][t] + part[1][t] + part[2][t] + part[3][t];
        if (t < 32) {
            betaout[(size_t)row * 32 + t] = 1.f / (1.f + __expf(-v));
        } else {
            int hh = t - 32;
            float x = v + dt_bias[hh];
            float sp = (x > 20.f) ? x : log1pf(__expf(x));
            gout[(size_t)row * 32 + hh] = -__expf(A_log[hh]) * sp;
        }
    }
}

// ===== causal depthwise conv (K=4) + SiLU + split + l2norm(q,k), one row/block =====
// q,k out: f32 (scan wants cvt-free f32 math); v out: f16
__global__ __launch_bounds__(256) void k_conv(const _Float16* __restrict__ mixed,
                                              const float* __restrict__ conv_w,
                                              float* __restrict__ qout,
                                              float* __restrict__ kout,
                                              _Float16* __restrict__ vout) {
    int row = blockIdx.x;
    int l = row & (LL_ - 1);
    __shared__ float yv[CONVD_];
    __shared__ float red[256];
    __shared__ float rinvs[32];
    int t = threadIdx.x;
    for (int c = t; c < CONVD_; c += 256) {
        float acc = 0.f;
#pragma unroll
        for (int j = 0; j < 4; j++) {
            int sl = l - 3 + j;          // per-sequence causal pad
            if (sl >= 0) acc += (float)mixed[(size_t)(row - 3 + j) * CONVD_ + c] * conv_w[c * 4 + j];
        }
        yv[c] = acc / (1.f + __expf(-acc));            // SiLU
    }
    __syncthreads();
    int seg = t >> 3, j8 = t & 7;
    int base = (seg < 16) ? seg * 128 : 2048 + (seg - 16) * 128;
    float ss = 0.f;
#pragma unroll
    for (int i = 0; i < 16; i++) { float vv = yv[base + j8 * 16 + i]; ss += vv * vv; }
    red[t] = ss;
    __syncthreads();
    if (t < 32) {
        float tot = 0.f;
#pragma unroll
        for (int jj = 0; jj < 8; jj++) tot += red[t * 8 + jj];
        rinvs[t] = rsqrtf(tot + 1e-6f);
    }
    __syncthreads();
    for (int c = t; c < CONVD_; c += 256) {
        float y = yv[c];
        if (c < 2048) {
            qout[(size_t)row * 2048 + c] = y * rinvs[c >> 7] * 0.08838834764831843f;
        } else if (c < 4096) {
            int c2 = c - 2048;
            kout[(size_t)row * 2048 + c2] = y * rinvs[16 + (c2 >> 7)];
        } else {
            vout[(size_t)row * 4096 + (c - 4096)] = (_Float16)y;
        }
    }
}

// ===================== gated delta-rule scan =====================
// R10 (fourth resubmission; broker timeouts, never yet run): evict v/g/beta
// from the compiler-managed counter streams.
// WHY: R9 measured 742us (870 cyc/step), VALUBusy 40.7%, no resource
// saturated; ~400-500 cyc/phase of unexplained stall remained. Diagnosis:
// g/beta have wave-uniform addresses -> compiler emits s_load (SMEM).
// SMEM shares lgkmcnt with ds_read but retires OUT OF ORDER w.r.t. DS, so
// the only safe compiler wait before consuming the prefetched K/Q registers
// is lgkmcnt(0) -- which also drains the just-issued g/beta s_loads
// (~200-500 cyc L2 latency) every phase, ON the serial chain (SGPR=112
// corroborates SMEM). Fix: load v/g/beta via inline-asm global_load (forced
// VMEM). lgkmcnt becomes DS-only (in-order -> cheap counted waits); the asm
// loads are invisible to the compiler's waitcnt pass, so readiness is
// enforced by OUR vmcnt, re-derived for the all-VMEM stream (store, async,
// v, g, b = 5 ops/phase): steady vmcnt(10) (exact bound for b(T); 10<=28
// bound for ASYNC(T+1)), peel 15 / 6,8,10,10,10,10. Rule-#18 hazard (hipcc
// hoists register-only consumers past asm waitcnt) is closed by data-chaining
// the raw loaded values through the waitcnt asm via "+v" operands. Grid,
// lane layout, LDS ring, DPP reduce, math order bit-identical to R9.
// Ledger re-audited r6: prologue 16 ops -> vmcnt(15)=A0; peel counts retire
// through b(T) (and older ASYNC(T+1)); ring slot (T+1)&7 next overwritten by
// ASYNC(T+9) two phases after the guarded read; conditional store always
// issues (4/64 lanes active -> execnz).
__global__ __launch_bounds__(64, 1) void k_scan(const float* __restrict__ q,
                                                const float* __restrict__ k,
                                                const _Float16* __restrict__ v,
                                                const float* __restrict__ g,
                                                const float* __restrict__ beta,
                                                _Float16* __restrict__ o) {
    int bid = blockIdx.x;          // 2048 = 64 members * 32 groups
    int member = bid >> 5;         // 0..63: hpar*32 + dvt
    int G = bid & 31;              // group (b,hk): bid%8 == G%8 -> same XCD
    int b = G >> 4, hk = G & 15;
    int h = hk * 2 + (member >> 5);
    int dvt = member & 31;
    int l = threadIdx.x;
    int dkq = l & 15, dvo = l >> 4;
    int dv = dvt * 4 + dvo;

    __shared__ __align__(16) float kq[8][256];   // 8 x (128 k + 128 q) = 8KB ring

    const float*    krow = k + ((size_t)(b * LL_) * 16 + hk) * 128;
    const float*    qrow = q + ((size_t)(b * LL_) * 16 + hk) * 128;
    const _Float16* vb_ = v + ((size_t)(b * LL_) * 32 + h) * 128 + dv;
    const float*    gb_ = g + (size_t)(b * LL_) * 32 + h;
    const float*    bb_ = beta + (size_t)(b * LL_) * 32 + h;
    _Float16*       ob_ = o + ((size_t)(b * LL_) * 32 + h) * 128 + dv;

    // staging: lanes 0-31 stage k (LDS slots 0-31), lanes 32-63 stage q
    // (slots 32-63). Slot j holds global 16B chunk c(j): even chunks 2j at
    // j<16, odd chunks 2(j-16)+1 at j>=16. Read side: lane dkq reads its k
    // chunks {2dkq, 2dkq+1} at slots {dkq, 16+dkq} -> 16 distinct slots per
    // instruction = 2-way bank alias (free) + 4-way dvo broadcast (free).
    int jl = l & 31;
    int cj = (jl < 16) ? (2 * jl) : (2 * (jl - 16) + 1);
    const float* gsrc = ((l >> 5) ? qrow : krow) + (size_t)cj * 4;

    f32x2 s2[4];
#pragma unroll
    for (int i = 0; i < 4; i++) s2[i] = (f32x2){0.f, 0.f};

    unsigned int rvA, rvB, rvC;      // raw f16 v bits (asm-loaded)
    float rgA, rgB, rgC;             // g (asm-loaded)
    float rbA, rbB, rbC;             // beta (asm-loaded)
    f32x4 KA0, KA1, QA0, QA1;
    f32x4 KB0, KB1, QB0, QB1;
    f32x4 KC0, KC1, QC0, QC1;

#define SB __builtin_amdgcn_sched_barrier(0x6)   // VALU+SALU may cross; VMEM/DS pinned

#define ASYNC(T)                                                          \
    do {                                                                  \
        int Tc_ = ((T) < LL_) ? (T) : (LL_ - 1);                          \
        async16f(gsrc + (size_t)Tc_ * 2048, &kq[(T) & 7][0]);             \
    } while (0)

// forced-VMEM loads, invisible to the compiler waitcnt pass; order v,g,b.
#define LDVGB(RV, RG, RB, T)                                              \
    do {                                                                  \
        int T_ = ((T) < LL_) ? (T) : (LL_ - 1);                           \
        const _Float16* pv_ = vb_ + (size_t)T_ * 4096;                    \
        const float*    pg_ = gb_ + (size_t)T_ * 32;                      \
        const float*    pb_ = bb_ + (size_t)T_ * 32;                      \
        asm volatile("global_load_ushort %0, %1, off"                     \
                     : "=v"(RV) : "v"(pv_) : "memory");                   \
        asm volatile("global_load_dword %0, %1, off"                      \
                     : "=v"(RG) : "v"(pg_) : "memory");                   \
        asm volatile("global_load_dword %0, %1, off"                      \
                     : "=v"(RB) : "v"(pb_) : "memory");                   \
    } while (0)

// PHASE(T): waitcnt (data-chains RV/RG/RB so their consumers can't hoist,
// and guarantees slot T+1 landed); prefetch K/Q(T+1) -> N*; compute step T
// from C* (loaded last phase); store; ASYNC(T+7); reload RV/RG/RB for T+3.
// WN: in-order vmcnt retirement; N <= exact newer-op count for the oldest
// needed op (b(T): 10 newer in steady state; ASYNC(T+1): 28 newer).
#define PHASE(C0, C1, C2, C3, N0, N1, N2, N3, RV, RG, RB, T, WN)          \
    do {                                                                  \
        asm volatile("s_waitcnt vmcnt(" WN ")"                            \
                     : "+v"(RV), "+v"(RG), "+v"(RB) :: "memory");         \
        const float* nb_ = &kq[((T) + 1) & 7][0];                         \
        N0 = *(const f32x4*)(nb_ + dkq * 4);                              \
        N1 = *(const f32x4*)(nb_ + 64 + dkq * 4);                         \
        N2 = *(const f32x4*)(nb_ + 128 + dkq * 4);                        \
        N3 = *(const f32x4*)(nb_ + 192 + dkq * 4);                        \
        float vval = (float)__builtin_bit_cast(_Float16, (unsigned short)(RV)); \
        float bval = (RB);                                                \
        float eg = __expf(RG);                                            \
        f32x2 a0 = C0.xy * s2[0] + C1.xy * s2[2];                         \
        f32x2 a1 = C0.zw * s2[1] + C1.zw * s2[3];                         \
        f32x2 asum = a0 + a1;                                             \
        float kv = (asum.x + asum.y) * eg;                                \
        kv += dpp_xor1(kv);                                               \
        kv += dpp_xor2(kv);                                               \
        kv += dpp_ror4(kv);                                               \
        kv += dpp_ror8(kv);                                               \
        float dlt = (vval - kv) * bval;                                   \
        f32x2 eg2 = {eg, eg}, dl2 = {dlt, dlt};                           \
        s2[0] = s2[0] * eg2 + C0.xy * dl2;                                \
        s2[1] = s2[1] * eg2 + C0.zw * dl2;                                \
        s2[2] = s2[2] * eg2 + C1.xy * dl2;                                \
        s2[3] = s2[3] * eg2 + C1.zw * dl2;                                \
        f32x2 o0 = C2.xy * s2[0] + C3.xy * s2[2];                         \
        f32x2 o1 = C2.zw * s2[1] + C3.zw * s2[3];                         \
        f32x2 osum = o0 + o1;                                             \
        float ov = osum.x + osum.y;                                       \
        ov += dpp_xor1(ov);                                               \
        ov += dpp_xor2(ov);                                               \
        ov += dpp_ror4(ov);                                               \
        ov += dpp_ror8(ov);                                               \
        if (dkq == 0) ob_[(size_t)(T) * 4096] = (_Float16)ov;             \
        SB; ASYNC((T) + 7); SB; LDVGB(RV, RG, RB, (T) + 3); SB;           \
    } while (0)

    // ---- order-pinned prologue FIFO: A0..A6, v0,g0,b0, v1,g1,b1, v2,g2,b2 ----
    ASYNC(0); SB; ASYNC(1); SB; ASYNC(2); SB; ASYNC(3); SB;
    ASYNC(4); SB; ASYNC(5); SB; ASYNC(6); SB;
    LDVGB(rvA, rgA, rbA, 0); SB;
    LDVGB(rvB, rgB, rbB, 1); SB;
    LDVGB(rvC, rgC, rbC, 2); SB;

    // prologue reg-load of step 0 (slot 0): 15 ops newer than A0 -> vmcnt(15)
    asm volatile("s_waitcnt vmcnt(15)" ::: "memory");
    {
        const float* nb_ = &kq[0][0];
        KA0 = *(const f32x4*)(nb_ + dkq * 4);
        KA1 = *(const f32x4*)(nb_ + 64 + dkq * 4);
        QA0 = *(const f32x4*)(nb_ + 128 + dkq * 4);
        QA1 = *(const f32x4*)(nb_ + 192 + dkq * 4);
    }

    // ---- peeled ramp-up: exact newer-op counts for {b(T), ASYNC(T+1)} ----
    PHASE(KA0, KA1, QA0, QA1, KB0, KB1, QB0, QB1, rvA, rgA, rbA, 0, "6");
    PHASE(KB0, KB1, QB0, QB1, KC0, KC1, QC0, QC1, rvB, rgB, rbB, 1, "8");
    PHASE(KC0, KC1, QC0, QC1, KA0, KA1, QA0, QA1, rvC, rgC, rbC, 2, "10");
    PHASE(KA0, KA1, QA0, QA1, KB0, KB1, QB0, QB1, rvA, rgA, rbA, 3, "10");
    PHASE(KB0, KB1, QB0, QB1, KC0, KC1, QC0, QC1, rvB, rgB, rbB, 4, "10");
    PHASE(KC0, KC1, QC0, QC1, KA0, KA1, QA0, QA1, rvC, rgC, rbC, 5, "10");

    // ---- steady state ----
    for (int t = 6; t < LL_; t += 3) {
        PHASE(KA0, KA1, QA0, QA1, KB0, KB1, QB0, QB1, rvA, rgA, rbA, t, "10");
        if (t + 1 < LL_)
            PHASE(KB0, KB1, QB0, QB1, KC0, KC1, QC0, QC1, rvB, rgB, rbB, t + 1, "10");
        if (t + 2 < LL_)
            PHASE(KC0, KC1, QC0, QC1, KA0, KA1, QA0, QA1, rvC, rgC, rbC, t + 2, "10");
    }
#undef PHASE
#undef LDVGB
#undef ASYNC
#undef SB
}

// ===================== gated RMSNorm, one row/block, f16 in/out =====================
__global__ __launch_bounds__(256) void k_rmsnorm(const _Float16* __restrict__ o,
                                                 const _Float16* __restrict__ z,
                                                 const float* __restrict__ norm_w,
                                                 _Float16* __restrict__ gn) {
    int row = blockIdx.x;
    __shared__ float gv[4096];
    __shared__ float red[256];
    __shared__ float rinv[32];
    int t = threadIdx.x;
    int h = t >> 3, j = t & 7;
    size_t base = (size_t)row * 4096 + h * 128 + j * 16;
    float ss = 0.f;
#pragma unroll
    for (int i = 0; i < 16; i++) {
        float ov = (float)o[base + i];
        float zv = (float)z[base + i];
        float gg = ov * zv / (1.f + __expf(-zv));
        gv[h * 128 + j * 16 + i] = gg;
        ss += gg * gg;
    }
    red[t] = ss;
    __syncthreads();
    if (t < 32) {
        float tot = 0.f;
#pragma unroll
        for (int jj = 0; jj < 8; jj++) tot += red[t * 8 + jj];
        rinv[t] = rsqrtf(tot * (1.f / 128.f) + 1e-6f);
    }
    __syncthreads();
#pragma unroll
    for (int i = 0; i < 16; i++) {
        int idx = h * 128 + j * 16 + i;
        gn[(size_t)row * 4096 + idx] = (_Float16)(gv[idx] * rinv[h] * norm_w[idx & 127]);
    }
}

// ===================== launch =====================
// Workspace (145 MB + d_out as scratch; aliases stream-ordered):
//   [  0, 16) XH f16 (r: GEMM1,GEMM2)      -> GN f16 [0,32) (w: rmsnorm after GEMM2)
//   [ 16, 48) WQKVT f16 (r: GEMM1)         -> VB f16 (w: conv, r: scan)
//   [ 48,112) MIXED f16 (w: GEMM1, r: conv)-> OB f16 [48,80) (w: scan)
//                                          -> WZT f16 [80,96)
//   [ 96,128) ZH f16 (w: GEMM2 after scan; overlaps dead MIXED tail + dead KB head)
//   [112,144) KB f32 (w: conv, r: scan)    -> WOUTT f16 [128,144) (after scan)
//   [144,145) GB + BBUF f32
//   d_out (32 MiB f32) = QB (w: conv, r: scan, overwritten by GEMM3 at end)
extern "C" void kernel_launch(void* const* d_in, const int* in_sizes, int n_in,
                              void* d_out, int out_size, void* d_ws, size_t ws_size,
                              hipStream_t stream) {
    const float* hidden  = (const float*)d_in[0];
    const float* W_qkv   = (const float*)d_in[1];
    const float* W_z     = (const float*)d_in[2];
    const float* W_b     = (const float*)d_in[3];
    const float* W_a     = (const float*)d_in[4];
    const float* conv_w  = (const float*)d_in[5];
    const float* dt_bias = (const float*)d_in[6];
    const float* A_log   = (const float*)d_in[7];
    const float* norm_w  = (const float*)d_in[8];
    const float* W_out   = (const float*)d_in[9];
    float* out = (float*)d_out;

    const size_t MB = 1ull << 20;
    char* ws = (char*)d_ws;
    if (ws_size < 146 * MB) {
        hipMemsetAsync(d_out, 0, (size_t)out_size * sizeof(float), stream);
        return;
    }

    _Float16* XH    = (_Float16*)(ws + 0 * MB);
    _Float16* WQKVT = (_Float16*)(ws + 16 * MB);
    _Float16* MIXED = (_Float16*)(ws + 48 * MB);
    float*    QB    = out;                           // d_out as q scratch
    float*    KB    = (float*)(ws + 112 * MB);
    _Float16* VB    = (_Float16*)(ws + 16 * MB);
    _Float16* OB    = (_Float16*)(ws + 48 * MB);
    _Float16* WZT   = (_Float16*)(ws + 80 * MB);
    _Float16* ZH    = (_Float16*)(ws + 96 * MB);
    _Float16* GN    = (_Float16*)(ws + 0 * MB);
    _Float16* WOUTT = (_Float16*)(ws + 128 * MB);
    float*    GB    = (float*)(ws + 144 * MB);
    float*    BBUF  = (float*)(ws + 144 * MB + 512 * 1024);

    k_convert<<<(MM_ * DD_ / 4 + 255) / 256, 256, 0, stream>>>(hidden, XH, MM_ * DD_ / 4);
    k_transpose<<<dim3(CONVD_ / 32, DD_ / 32), 256, 0, stream>>>(W_qkv, WQKVT, DD_, CONVD_);
    k_gemm<true><<<dim3(CONVD_ / 128, MM_ / 128), 256, 0, stream>>>(XH, WQKVT, MIXED, MM_, CONVD_, DD_);
    k_ba<<<MM_, 256, 0, stream>>>(hidden, W_b, W_a, dt_bias, A_log, GB, BBUF);
    k_conv<<<MM_, 256, 0, stream>>>(MIXED, conv_w, QB, KB, VB);
    k_scan<<<2048, 64, 0, stream>>>(QB, KB, VB, GB, BBUF, OB);
    k_transpose<<<dim3(VALD_ / 32, DD_ / 32), 256, 0, stream>>>(W_z, WZT, DD_, VALD_);
    k_gemm<true><<<dim3(VALD_ / 128, MM_ / 128), 256, 0, stream>>>(XH, WZT, ZH, MM_, VALD_, DD_);
    k_rmsnorm<<<MM_, 256, 0, stream>>>(OB, ZH, norm_w, GN);
    k_transpose<<<dim3(DD_ / 32, VALD_ / 32), 256, 0, stream>>>(W_out, WOUTT, VALD_, DD_);
    k_gemm<false><<<dim3(DD_ / 128, MM_ / 128), 256, 0, stream>>>(GN, WOUTT, out, MM_, DD_, VALD_);
}